// Round 1
// baseline (1318.243 us; speedup 1.0000x reference)
//
#include <hip/hip_runtime.h>
#include <hip/hip_bf16.h>

// SpectralMoleculeEncoder: 3-layer ChebConv (K=3), N=50000, E=800000, 32->128->256->512.
// Structure per layer: CSR-gather props (tx1 = P x, tx2 = 2 P tx1 - x) -> concat bf16 GEMM
// [N x 3F] @ [3F x Fout] (W[3,F,Fout] flat IS the stacked matrix) + bias + relu.
// Graph CSR built per call (deterministic work): count -> 1-block scan -> atomic fill.

typedef __bf16 bf16x8 __attribute__((ext_vector_type(8)));
typedef float f32x4 __attribute__((ext_vector_type(4)));
typedef unsigned short ushort_t;

// ---------------- graph build ----------------
__global__ void count_kernel(const int* __restrict__ src, const int* __restrict__ dst,
                             int* __restrict__ cnt_src, int* __restrict__ cnt_dst, int E, int N) {
    int e = blockIdx.x * blockDim.x + threadIdx.x;
    if (e >= E) return;
    int s = src[e], d = dst[e];
    if ((unsigned)s < (unsigned)N) atomicAdd(&cnt_src[s], 1);
    if ((unsigned)d < (unsigned)N) atomicAdd(&cnt_dst[d], 1);
}

__global__ void dinv_kernel(const int* __restrict__ cnt_src, float* __restrict__ dinv, int N) {
    int i = blockIdx.x * blockDim.x + threadIdx.x;
    if (i >= N) return;
    int c = cnt_src[i];
    dinv[i] = (c > 0) ? rsqrtf((float)c) : 0.0f;
}

// single-block exclusive scan over cnt_dst -> row_ptr[N+1], wofs copy
__global__ __launch_bounds__(1024) void scan_kernel(const int* __restrict__ cnt,
                                                    int* __restrict__ row_ptr,
                                                    int* __restrict__ wofs, int N) {
    __shared__ int sums[1024];
    int t = threadIdx.x;
    int chunk = (N + 1023) >> 10;
    int lo = t * chunk, hi = min(N, lo + chunk);
    int s = 0;
    for (int i = lo; i < hi; ++i) s += cnt[i];
    sums[t] = s;
    __syncthreads();
    for (int off = 1; off < 1024; off <<= 1) {
        int u = (t >= off) ? sums[t - off] : 0;
        __syncthreads();
        sums[t] += u;
        __syncthreads();
    }
    int run = sums[t] - s;  // exclusive prefix for this chunk
    for (int i = lo; i < hi; ++i) {
        row_ptr[i] = run; wofs[i] = run;
        run += cnt[i];
    }
    if (t == 1023) row_ptr[N] = sums[1023];
}

__global__ void fill_kernel(const int* __restrict__ src, const int* __restrict__ dst,
                            const float* __restrict__ dinv, int* __restrict__ wofs,
                            int* __restrict__ esrc, float* __restrict__ enorm, int E, int N) {
    int e = blockIdx.x * blockDim.x + threadIdx.x;
    if (e >= E) return;
    int s = src[e], d = dst[e];
    if ((unsigned)s >= (unsigned)N || (unsigned)d >= (unsigned)N) return;
    int pos = atomicAdd(&wofs[d], 1);
    esrc[pos] = s;
    enorm[pos] = -dinv[s] * dinv[d];
}

// ---------------- propagation (CSR gather, no atomics) ----------------
// prop1: t1 = P x ; also writes txb[:,0:F]=bf16(x), txb[:,F:2F]=bf16(t1)
template <int F>
__global__ void prop1_kernel(const float* __restrict__ x, const int* __restrict__ row_ptr,
                             const int* __restrict__ esrc, const float* __restrict__ enorm,
                             float* __restrict__ t1, ushort_t* __restrict__ txb, int N) {
    constexpr int NPB = 256 / F;  // nodes per block (F <= 256)
    int f = threadIdx.x % F;
    int node = blockIdx.x * NPB + threadIdx.x / F;
    if (node >= N) return;
    int e0 = row_ptr[node], e1 = row_ptr[node + 1];
    float acc = 0.f;
    for (int e = e0; e < e1; ++e)
        acc += enorm[e] * x[(size_t)esrc[e] * F + f];
    t1[(size_t)node * F + f] = acc;
    size_t tb = (size_t)node * (3 * F);
    float x0 = x[(size_t)node * F + f];
    txb[tb + f]     = __builtin_bit_cast(ushort_t, (__bf16)x0);
    txb[tb + F + f] = __builtin_bit_cast(ushort_t, (__bf16)acc);
}

// prop2: tx2 = 2 * (P t1) - x ; writes txb[:,2F:3F]
template <int F>
__global__ void prop2_kernel(const float* __restrict__ t1, const float* __restrict__ x,
                             const int* __restrict__ row_ptr, const int* __restrict__ esrc,
                             const float* __restrict__ enorm, ushort_t* __restrict__ txb, int N) {
    constexpr int NPB = 256 / F;
    int f = threadIdx.x % F;
    int node = blockIdx.x * NPB + threadIdx.x / F;
    if (node >= N) return;
    int e0 = row_ptr[node], e1 = row_ptr[node + 1];
    float acc = 0.f;
    for (int e = e0; e < e1; ++e)
        acc += enorm[e] * t1[(size_t)esrc[e] * F + f];
    float val = 2.f * acc - x[(size_t)node * F + f];
    txb[(size_t)node * (3 * F) + 2 * F + f] = __builtin_bit_cast(ushort_t, (__bf16)val);
}

// W [K x Nout] f32 -> Wt [Nout x K] bf16 (transposed so GEMM B-frag reads are contiguous in k)
__global__ void convw_kernel(const float* __restrict__ W, ushort_t* __restrict__ Wt, int K, int Nout) {
    int id = blockIdx.x * blockDim.x + threadIdx.x;
    if (id >= K * Nout) return;
    int n = id / K, k = id % K;
    Wt[id] = __builtin_bit_cast(ushort_t, (__bf16)W[(size_t)k * Nout + n]);
}

// ---------------- bf16 MFMA GEMM: out = relu(A @ B + bias) ----------------
// A [M x K] bf16, Bt [Nout x K] bf16 (B transposed), out [M x Nout] f32.
// 128x128 tile, BK=32, 4 waves (2x2), each wave 64x64 = 4x4 frags of 16x16x32.
__global__ __launch_bounds__(256) void gemm_kernel(const ushort_t* __restrict__ A,
                                                   const ushort_t* __restrict__ Bt,
                                                   const float* __restrict__ bias,
                                                   float* __restrict__ out,
                                                   int M, int K, int Nout) {
    __shared__ ushort_t As[128][40];  // pad 32 -> 40 elems (80B row): 2-way bank alias only
    __shared__ ushort_t Bs[128][40];
    int tid = threadIdx.x;
    int brow = blockIdx.x * 128;
    int bcol = blockIdx.y * 128;
    int lane = tid & 63, wid = tid >> 6;
    int wr = wid >> 1, wc = wid & 1;
    int g = lane >> 4, lr = lane & 15;
    f32x4 acc[4][4] = {};

    for (int kt = 0; kt < K; kt += 32) {
#pragma unroll
        for (int i = 0; i < 2; ++i) {  // 512 chunks of 8 bf16 (16B) per tile, 2 per thread
            int c = tid * 2 + i;
            int r = c >> 2, cc = (c & 3) << 3;
            int gr = brow + r;
            int4 va = make_int4(0, 0, 0, 0);
            if (gr < M) va = *(const int4*)&A[(size_t)gr * K + kt + cc];
            *(int4*)&As[r][cc] = va;
            int4 vb = *(const int4*)&Bt[(size_t)(bcol + r) * K + kt + cc];
            *(int4*)&Bs[r][cc] = vb;
        }
        __syncthreads();
        bf16x8 a[4], b[4];
#pragma unroll
        for (int m = 0; m < 4; ++m) a[m] = *(const bf16x8*)&As[wr * 64 + m * 16 + lr][g * 8];
#pragma unroll
        for (int n = 0; n < 4; ++n) b[n] = *(const bf16x8*)&Bs[wc * 64 + n * 16 + lr][g * 8];
#pragma unroll
        for (int m = 0; m < 4; ++m)
#pragma unroll
            for (int n = 0; n < 4; ++n)
                acc[m][n] = __builtin_amdgcn_mfma_f32_16x16x32_bf16(a[m], b[n], acc[m][n], 0, 0, 0);
        __syncthreads();
    }

#pragma unroll
    for (int m = 0; m < 4; ++m) {
        int grow_base = brow + wr * 64 + m * 16 + g * 4;  // C/D: col=lane&15, row=(lane>>4)*4+reg
#pragma unroll
        for (int n = 0; n < 4; ++n) {
            int gcol = bcol + wc * 64 + n * 16 + lr;
            float bv = bias[gcol];
#pragma unroll
            for (int r = 0; r < 4; ++r) {
                int grow = grow_base + r;
                if (grow < M) {
                    float v2 = acc[m][n][r] + bv;
                    out[(size_t)grow * Nout + gcol] = v2 > 0.f ? v2 : 0.f;
                }
            }
        }
    }
}

extern "C" void kernel_launch(void* const* d_in, const int* in_sizes, int n_in,
                              void* d_out, int out_size, void* d_ws, size_t ws_size,
                              hipStream_t stream) {
    const float* v  = (const float*)d_in[0];
    const int*   ei = (const int*)d_in[1];
    const float* W1 = (const float*)d_in[2];
    const float* b1 = (const float*)d_in[3];
    const float* W2 = (const float*)d_in[4];
    const float* b2 = (const float*)d_in[5];
    const float* W3 = (const float*)d_in[6];
    const float* b3 = (const float*)d_in[7];

    const int N = in_sizes[0] / 32;
    const int E = in_sizes[1] / 2;
    const int* src = ei;
    const int* dst = ei + E;

    char* ws = (char*)d_ws;
    size_t off = 0;
    auto alloc = [&](size_t bytes) {
        off = (off + 255) & ~(size_t)255;
        char* p = ws + off;
        off += bytes;
        return p;
    };
    int*      esrc    = (int*)alloc((size_t)E * 4);
    float*    enorm   = (float*)alloc((size_t)E * 4);
    int*      row_ptr = (int*)alloc((size_t)(N + 1) * 4);
    int*      wofs    = (int*)alloc((size_t)N * 4);
    int*      cnt_src = (int*)alloc((size_t)N * 4);
    int*      cnt_dst = (int*)alloc((size_t)N * 4);
    float*    dinv    = (float*)alloc((size_t)N * 4);
    ushort_t* Wt      = (ushort_t*)alloc((size_t)512 * 768 * 2);
    ushort_t* txb     = (ushort_t*)alloc((size_t)N * 768 * 2);  // [N x 3*F_in] bf16, max F_in=256

    // d_out (N*512 f32 = 102.4MB) doubles as scratch, carved by live range:
    //   t1   : d_out[0        .. N*256)  (prop intermediate, per layer, <= N*256 f32)
    //   out1 : d_out[N*128    .. N*256)  (layer1 output, N*128 f32)
    //   out2 : d_out[N*256    .. N*512)  (layer2 output, N*256 f32)
    // Final GEMM reads only txb/Wt/bias (ws) and overwrites all of d_out.
    float* t1   = (float*)d_out;
    float* out1 = (float*)d_out + (size_t)N * 128;
    float* out2 = (float*)d_out + (size_t)N * 256;
    float* outF = (float*)d_out;

    // ---- graph build ----
    hipMemsetAsync(cnt_src, 0, (size_t)N * 4, stream);
    hipMemsetAsync(cnt_dst, 0, (size_t)N * 4, stream);
    count_kernel<<<(E + 255) / 256, 256, 0, stream>>>(src, dst, cnt_src, cnt_dst, E, N);
    dinv_kernel<<<(N + 255) / 256, 256, 0, stream>>>(cnt_src, dinv, N);
    scan_kernel<<<1, 1024, 0, stream>>>(cnt_dst, row_ptr, wofs, N);
    fill_kernel<<<(E + 255) / 256, 256, 0, stream>>>(src, dst, dinv, wofs, esrc, enorm, E, N);

    // ---- layer 1: 32 -> 128 ----
    prop1_kernel<32><<<((size_t)N * 32 + 255) / 256, 256, 0, stream>>>(v, row_ptr, esrc, enorm, t1, txb, N);
    prop2_kernel<32><<<((size_t)N * 32 + 255) / 256, 256, 0, stream>>>(t1, v, row_ptr, esrc, enorm, txb, N);
    convw_kernel<<<(96 * 128 + 255) / 256, 256, 0, stream>>>(W1, Wt, 96, 128);
    gemm_kernel<<<dim3((N + 127) / 128, 1), 256, 0, stream>>>(txb, Wt, b1, out1, N, 96, 128);

    // ---- layer 2: 128 -> 256 ----
    prop1_kernel<128><<<((size_t)N * 128 + 255) / 256, 256, 0, stream>>>(out1, row_ptr, esrc, enorm, t1, txb, N);
    prop2_kernel<128><<<((size_t)N * 128 + 255) / 256, 256, 0, stream>>>(t1, out1, row_ptr, esrc, enorm, txb, N);
    convw_kernel<<<(384 * 256 + 255) / 256, 256, 0, stream>>>(W2, Wt, 384, 256);
    gemm_kernel<<<dim3((N + 127) / 128, 2), 256, 0, stream>>>(txb, Wt, b2, out2, N, 384, 256);

    // ---- layer 3: 256 -> 512 ----
    prop1_kernel<256><<<((size_t)N * 256 + 255) / 256, 256, 0, stream>>>(out2, row_ptr, esrc, enorm, t1, txb, N);
    prop2_kernel<256><<<((size_t)N * 256 + 255) / 256, 256, 0, stream>>>(t1, out2, row_ptr, esrc, enorm, txb, N);
    convw_kernel<<<(768 * 512 + 255) / 256, 256, 0, stream>>>(W3, Wt, 768, 512);
    gemm_kernel<<<dim3((N + 127) / 128, 4), 256, 0, stream>>>(txb, Wt, b3, outF, N, 768, 512);
}

// Round 3
// 613.359 us; speedup vs baseline: 2.1492x; 2.1492x over previous
//
#include <hip/hip_runtime.h>
#include <hip/hip_bf16.h>

// SpectralMoleculeEncoder: 3-layer ChebConv (K=3), N=50000, E=800000, 32->128->256->512.
// R3 = R2 + grid fix: layer-1 prop grid was (N*4+1023)/1024=196 blocks x 64 nodes -> only
// 12544/50000 nodes covered. Correct: (N+63)/64.
// All-bf16 feature pipeline. txb_L = [N, 3F] bf16 per layer; prev GEMM writes relu'd
// bf16 output into next layer's slice0; props gather bf16 16B/lane and write slice1/slice2.

typedef __bf16 bf16x8 __attribute__((ext_vector_type(8)));
typedef float f32x4 __attribute__((ext_vector_type(4)));
typedef unsigned short ushort_t;

struct EdgeRec { int s; float w; };

__device__ inline float bf2f(ushort_t u) { return __builtin_bit_cast(float, (unsigned)u << 16); }
__device__ inline ushort_t f2bf(float f) { return __builtin_bit_cast(ushort_t, (__bf16)f); }

union U8 { int4 v; ushort_t u[8]; };

// ---------------- graph build ----------------
__global__ void count_kernel(const int* __restrict__ src, const int* __restrict__ dst,
                             int* __restrict__ cnt_src, int* __restrict__ cnt_dst, int E, int N) {
    int e = blockIdx.x * blockDim.x + threadIdx.x;
    if (e >= E) return;
    int s = src[e], d = dst[e];
    if ((unsigned)s < (unsigned)N) atomicAdd(&cnt_src[s], 1);
    if ((unsigned)d < (unsigned)N) atomicAdd(&cnt_dst[d], 1);
}

__global__ void dinv_kernel(const int* __restrict__ cnt_src, float* __restrict__ dinv, int N) {
    int i = blockIdx.x * blockDim.x + threadIdx.x;
    if (i >= N) return;
    int c = cnt_src[i];
    dinv[i] = (c > 0) ? rsqrtf((float)c) : 0.0f;
}

__global__ __launch_bounds__(1024) void scan_kernel(const int* __restrict__ cnt,
                                                    int* __restrict__ row_ptr,
                                                    int* __restrict__ wofs, int N) {
    __shared__ int sums[1024];
    int t = threadIdx.x;
    int chunk = (N + 1023) >> 10;
    int lo = t * chunk, hi = min(N, lo + chunk);
    int s = 0;
    for (int i = lo; i < hi; ++i) s += cnt[i];
    sums[t] = s;
    __syncthreads();
    for (int off = 1; off < 1024; off <<= 1) {
        int u = (t >= off) ? sums[t - off] : 0;
        __syncthreads();
        sums[t] += u;
        __syncthreads();
    }
    int run = sums[t] - s;
    for (int i = lo; i < hi; ++i) {
        row_ptr[i] = run; wofs[i] = run;
        run += cnt[i];
    }
    if (t == 1023) row_ptr[N] = sums[1023];
}

__global__ void fill_kernel(const int* __restrict__ src, const int* __restrict__ dst,
                            const float* __restrict__ dinv, int* __restrict__ wofs,
                            EdgeRec* __restrict__ ep, int E, int N) {
    int e = blockIdx.x * blockDim.x + threadIdx.x;
    if (e >= E) return;
    int s = src[e], d = dst[e];
    if ((unsigned)s >= (unsigned)N || (unsigned)d >= (unsigned)N) return;
    int pos = atomicAdd(&wofs[d], 1);
    EdgeRec er; er.s = s; er.w = -dinv[s] * dinv[d];
    ep[pos] = er;
}

// v [N,32] f32 -> txb1 slice0 bf16 (row stride 96)
__global__ void convin_kernel(const float* __restrict__ v, ushort_t* __restrict__ txb, int N) {
    int id = blockIdx.x * blockDim.x + threadIdx.x;
    if (id >= N * 4) return;
    int node = id >> 2, c = (id & 3) << 3;
    const float* p = &v[(size_t)node * 32 + c];
    U8 o;
#pragma unroll
    for (int i = 0; i < 8; ++i) o.u[i] = f2bf(p[i]);
    *(int4*)&txb[(size_t)node * 96 + c] = o.v;
}

// ---------------- propagation (CSR gather, bf16, 16B/lane) ----------------
// PASS 1: slice1 = P slice0 ; PASS 2: slice2 = 2 * (P slice1) - slice0
template <int F, int PASS>
__global__ __launch_bounds__(256) void prop_kernel(ushort_t* __restrict__ txb,
                                                   const int* __restrict__ row_ptr,
                                                   const EdgeRec* __restrict__ ep, int N) {
    constexpr int T = F / 8;        // lanes per node
    constexpr int NPB = 256 / T;    // nodes per block
    constexpr int RS = 3 * F;       // txb row stride
    constexpr int SRC = (PASS == 1) ? 0 : F;
    int tf = threadIdx.x % T;
    int node = blockIdx.x * NPB + threadIdx.x / T;
    if (node >= N) return;
    int e0 = row_ptr[node], e1 = row_ptr[node + 1];
    int fo = tf * 8;
    float acc[8] = {};
    int e = e0;
    for (; e + 1 < e1; e += 2) {
        EdgeRec ea = ep[e], eb = ep[e + 1];
        U8 xa, xb2;
        xa.v  = *(const int4*)&txb[(size_t)ea.s * RS + SRC + fo];
        xb2.v = *(const int4*)&txb[(size_t)eb.s * RS + SRC + fo];
#pragma unroll
        for (int i = 0; i < 8; ++i) acc[i] += ea.w * bf2f(xa.u[i]);
#pragma unroll
        for (int i = 0; i < 8; ++i) acc[i] += eb.w * bf2f(xb2.u[i]);
    }
    if (e < e1) {
        EdgeRec ea = ep[e];
        U8 xa;
        xa.v = *(const int4*)&txb[(size_t)ea.s * RS + SRC + fo];
#pragma unroll
        for (int i = 0; i < 8; ++i) acc[i] += ea.w * bf2f(xa.u[i]);
    }
    U8 o;
    if (PASS == 1) {
#pragma unroll
        for (int i = 0; i < 8; ++i) o.u[i] = f2bf(acc[i]);
        *(int4*)&txb[(size_t)node * RS + F + fo] = o.v;
    } else {
        U8 x0;
        x0.v = *(const int4*)&txb[(size_t)node * RS + fo];
#pragma unroll
        for (int i = 0; i < 8; ++i) o.u[i] = f2bf(2.f * acc[i] - bf2f(x0.u[i]));
        *(int4*)&txb[(size_t)node * RS + 2 * F + fo] = o.v;
    }
}

// W [K x Nout] f32 -> Wt [Nout x K] bf16
__global__ void convw_kernel(const float* __restrict__ W, ushort_t* __restrict__ Wt, int K, int Nout) {
    int id = blockIdx.x * blockDim.x + threadIdx.x;
    if (id >= K * Nout) return;
    int n = id / K, k = id % K;
    Wt[id] = f2bf(W[(size_t)k * Nout + n]);
}

// ---------------- bf16 MFMA GEMM: out = relu(A @ B + bias) ----------------
// A [M x K] bf16, Bt [Nout x K] bf16, out: bf16 (stride ostride) or f32.
template <bool BF16OUT>
__global__ __launch_bounds__(256) void gemm_kernel(const ushort_t* __restrict__ A,
                                                   const ushort_t* __restrict__ Bt,
                                                   const float* __restrict__ bias,
                                                   void* __restrict__ outp,
                                                   int M, int K, int Nout, int ostride) {
    __shared__ ushort_t As[128][40];
    __shared__ ushort_t Bs[128][40];
    int tid = threadIdx.x;
    int brow = blockIdx.x * 128;
    int bcol = blockIdx.y * 128;
    int lane = tid & 63, wid = tid >> 6;
    int wr = wid >> 1, wc = wid & 1;
    int g = lane >> 4, lr = lane & 15;
    f32x4 acc[4][4] = {};

    for (int kt = 0; kt < K; kt += 32) {
#pragma unroll
        for (int i = 0; i < 2; ++i) {
            int c = tid * 2 + i;
            int r = c >> 2, cc = (c & 3) << 3;
            int gr = brow + r;
            int4 va = make_int4(0, 0, 0, 0);
            if (gr < M) va = *(const int4*)&A[(size_t)gr * K + kt + cc];
            *(int4*)&As[r][cc] = va;
            int4 vb = *(const int4*)&Bt[(size_t)(bcol + r) * K + kt + cc];
            *(int4*)&Bs[r][cc] = vb;
        }
        __syncthreads();
        bf16x8 a[4], b[4];
#pragma unroll
        for (int m = 0; m < 4; ++m) a[m] = *(const bf16x8*)&As[wr * 64 + m * 16 + lr][g * 8];
#pragma unroll
        for (int n = 0; n < 4; ++n) b[n] = *(const bf16x8*)&Bs[wc * 64 + n * 16 + lr][g * 8];
#pragma unroll
        for (int m = 0; m < 4; ++m)
#pragma unroll
            for (int n = 0; n < 4; ++n)
                acc[m][n] = __builtin_amdgcn_mfma_f32_16x16x32_bf16(a[m], b[n], acc[m][n], 0, 0, 0);
        __syncthreads();
    }

#pragma unroll
    for (int m = 0; m < 4; ++m) {
        int grow_base = brow + wr * 64 + m * 16 + g * 4;  // C/D: col=lane&15, row=(lane>>4)*4+reg
#pragma unroll
        for (int n = 0; n < 4; ++n) {
            int gcol = bcol + wc * 64 + n * 16 + lr;
            float bv = bias[gcol];
#pragma unroll
            for (int r = 0; r < 4; ++r) {
                int grow = grow_base + r;
                if (grow < M) {
                    float v2 = acc[m][n][r] + bv;
                    v2 = v2 > 0.f ? v2 : 0.f;
                    if (BF16OUT)
                        ((ushort_t*)outp)[(size_t)grow * ostride + gcol] = f2bf(v2);
                    else
                        ((float*)outp)[(size_t)grow * ostride + gcol] = v2;
                }
            }
        }
    }
}

extern "C" void kernel_launch(void* const* d_in, const int* in_sizes, int n_in,
                              void* d_out, int out_size, void* d_ws, size_t ws_size,
                              hipStream_t stream) {
    const float* v  = (const float*)d_in[0];
    const int*   ei = (const int*)d_in[1];
    const float* W1 = (const float*)d_in[2];
    const float* b1 = (const float*)d_in[3];
    const float* W2 = (const float*)d_in[4];
    const float* b2 = (const float*)d_in[5];
    const float* W3 = (const float*)d_in[6];
    const float* b3 = (const float*)d_in[7];

    const int N = in_sizes[0] / 32;
    const int E = in_sizes[1] / 2;
    const int* src = ei;
    const int* dst = ei + E;

    char* ws = (char*)d_ws;
    size_t off = 0;
    auto alloc = [&](size_t bytes) {
        off = (off + 255) & ~(size_t)255;
        char* p = ws + off;
        off += bytes;
        return p;
    };
    EdgeRec*  ep      = (EdgeRec*)alloc((size_t)E * 8);
    int*      row_ptr = (int*)alloc((size_t)(N + 1) * 4);
    int*      wofs    = (int*)alloc((size_t)N * 4);
    int*      cnt_src = (int*)alloc((size_t)N * 4);
    int*      cnt_dst = (int*)alloc((size_t)N * 4);
    float*    dinv    = (float*)alloc((size_t)N * 4);
    ushort_t* Wt      = (ushort_t*)alloc((size_t)512 * 768 * 2);
    ushort_t* txb3    = (ushort_t*)alloc((size_t)N * 768 * 2);  // [N x 768] bf16, 76.8MB
    // txb1 [N x 96] aliases txb3 (dead before gemm2 writes txb3 slice0)
    ushort_t* txb1    = txb3;
    // txb2 [N x 384] lives in d_out (38.4MB < 102.4MB); dead before gemm3 writes d_out
    ushort_t* txb2    = (ushort_t*)d_out;
    float*    outF    = (float*)d_out;

    // ---- graph build ----
    hipMemsetAsync(cnt_src, 0, (size_t)N * 4, stream);
    hipMemsetAsync(cnt_dst, 0, (size_t)N * 4, stream);
    count_kernel<<<(E + 255) / 256, 256, 0, stream>>>(src, dst, cnt_src, cnt_dst, E, N);
    dinv_kernel<<<(N + 255) / 256, 256, 0, stream>>>(cnt_src, dinv, N);
    scan_kernel<<<1, 1024, 0, stream>>>(cnt_dst, row_ptr, wofs, N);
    fill_kernel<<<(E + 255) / 256, 256, 0, stream>>>(src, dst, dinv, wofs, ep, E, N);

    // ---- layer 1: 32 -> 128 ----  (prop: T=4 lanes/node, NPB=64 -> grid (N+63)/64)
    convin_kernel<<<(N * 4 + 255) / 256, 256, 0, stream>>>(v, txb1, N);
    prop_kernel<32, 1><<<(N + 63) / 64, 256, 0, stream>>>(txb1, row_ptr, ep, N);
    prop_kernel<32, 2><<<(N + 63) / 64, 256, 0, stream>>>(txb1, row_ptr, ep, N);
    convw_kernel<<<(96 * 128 + 255) / 256, 256, 0, stream>>>(W1, Wt, 96, 128);
    gemm_kernel<true><<<dim3((N + 127) / 128, 1), 256, 0, stream>>>(txb1, Wt, b1, txb2, N, 96, 128, 384);

    // ---- layer 2: 128 -> 256 ----  (NPB=16)
    prop_kernel<128, 1><<<(N + 15) / 16, 256, 0, stream>>>(txb2, row_ptr, ep, N);
    prop_kernel<128, 2><<<(N + 15) / 16, 256, 0, stream>>>(txb2, row_ptr, ep, N);
    convw_kernel<<<(384 * 256 + 255) / 256, 256, 0, stream>>>(W2, Wt, 384, 256);
    gemm_kernel<true><<<dim3((N + 127) / 128, 2), 256, 0, stream>>>(txb2, Wt, b2, txb3, N, 384, 256, 768);

    // ---- layer 3: 256 -> 512 ----  (NPB=8)
    prop_kernel<256, 1><<<(N + 7) / 8, 256, 0, stream>>>(txb3, row_ptr, ep, N);
    prop_kernel<256, 2><<<(N + 7) / 8, 256, 0, stream>>>(txb3, row_ptr, ep, N);
    convw_kernel<<<(768 * 512 + 255) / 256, 256, 0, stream>>>(W3, Wt, 768, 512);
    gemm_kernel<false><<<dim3((N + 127) / 128, 4), 256, 0, stream>>>(txb3, Wt, b3, outF, N, 768, 512, 512);
}

// Round 4
// 575.032 us; speedup vs baseline: 2.2925x; 1.0667x over previous
//
#include <hip/hip_runtime.h>
#include <hip/hip_bf16.h>

// SpectralMoleculeEncoder: 3-layer ChebConv (K=3), N=50000, E=800000, 32->128->256->512.
// R4 = R3 + GEMM rewrite: global_load_lds width-16 staging (linear LDS dest),
// XOR-swizzled 16B slots realized via pre-swizzled GLOBAL source (rule #21),
// chunked bijective XCD swizzle so col-tiles sharing an A panel land on one XCD.
// All-bf16 feature pipeline unchanged (passed R3, absmax 0.031).

typedef __bf16 bf16x8 __attribute__((ext_vector_type(8)));
typedef float f32x4 __attribute__((ext_vector_type(4)));
typedef unsigned short ushort_t;

struct EdgeRec { int s; float w; };

__device__ inline float bf2f(ushort_t u) { return __builtin_bit_cast(float, (unsigned)u << 16); }
__device__ inline ushort_t f2bf(float f) { return __builtin_bit_cast(ushort_t, (__bf16)f); }

union U8 { int4 v; ushort_t u[8]; };

__device__ inline void gload16(const ushort_t* g, ushort_t* l) {
    __builtin_amdgcn_global_load_lds(
        (const __attribute__((address_space(1))) unsigned int*)g,
        (__attribute__((address_space(3))) unsigned int*)l, 16, 0, 0);
}

// ---------------- graph build ----------------
__global__ void count_kernel(const int* __restrict__ src, const int* __restrict__ dst,
                             int* __restrict__ cnt_src, int* __restrict__ cnt_dst, int E, int N) {
    int e = blockIdx.x * blockDim.x + threadIdx.x;
    if (e >= E) return;
    int s = src[e], d = dst[e];
    if ((unsigned)s < (unsigned)N) atomicAdd(&cnt_src[s], 1);
    if ((unsigned)d < (unsigned)N) atomicAdd(&cnt_dst[d], 1);
}

__global__ void dinv_kernel(const int* __restrict__ cnt_src, float* __restrict__ dinv, int N) {
    int i = blockIdx.x * blockDim.x + threadIdx.x;
    if (i >= N) return;
    int c = cnt_src[i];
    dinv[i] = (c > 0) ? rsqrtf((float)c) : 0.0f;
}

__global__ __launch_bounds__(1024) void scan_kernel(const int* __restrict__ cnt,
                                                    int* __restrict__ row_ptr,
                                                    int* __restrict__ wofs, int N) {
    __shared__ int sums[1024];
    int t = threadIdx.x;
    int chunk = (N + 1023) >> 10;
    int lo = t * chunk, hi = min(N, lo + chunk);
    int s = 0;
    for (int i = lo; i < hi; ++i) s += cnt[i];
    sums[t] = s;
    __syncthreads();
    for (int off = 1; off < 1024; off <<= 1) {
        int u = (t >= off) ? sums[t - off] : 0;
        __syncthreads();
        sums[t] += u;
        __syncthreads();
    }
    int run = sums[t] - s;
    for (int i = lo; i < hi; ++i) {
        row_ptr[i] = run; wofs[i] = run;
        run += cnt[i];
    }
    if (t == 1023) row_ptr[N] = sums[1023];
}

__global__ void fill_kernel(const int* __restrict__ src, const int* __restrict__ dst,
                            const float* __restrict__ dinv, int* __restrict__ wofs,
                            EdgeRec* __restrict__ ep, int E, int N) {
    int e = blockIdx.x * blockDim.x + threadIdx.x;
    if (e >= E) return;
    int s = src[e], d = dst[e];
    if ((unsigned)s >= (unsigned)N || (unsigned)d >= (unsigned)N) return;
    int pos = atomicAdd(&wofs[d], 1);
    EdgeRec er; er.s = s; er.w = -dinv[s] * dinv[d];
    ep[pos] = er;
}

// v [N,32] f32 -> txb1 slice0 bf16 (row stride 96)
__global__ void convin_kernel(const float* __restrict__ v, ushort_t* __restrict__ txb, int N) {
    int id = blockIdx.x * blockDim.x + threadIdx.x;
    if (id >= N * 4) return;
    int node = id >> 2, c = (id & 3) << 3;
    const float* p = &v[(size_t)node * 32 + c];
    U8 o;
#pragma unroll
    for (int i = 0; i < 8; ++i) o.u[i] = f2bf(p[i]);
    *(int4*)&txb[(size_t)node * 96 + c] = o.v;
}

// ---------------- propagation (CSR gather, bf16, 16B/lane) ----------------
template <int F, int PASS>
__global__ __launch_bounds__(256) void prop_kernel(ushort_t* __restrict__ txb,
                                                   const int* __restrict__ row_ptr,
                                                   const EdgeRec* __restrict__ ep, int N) {
    constexpr int T = F / 8;        // lanes per node
    constexpr int NPB = 256 / T;    // nodes per block
    constexpr int RS = 3 * F;       // txb row stride
    constexpr int SRC = (PASS == 1) ? 0 : F;
    int tf = threadIdx.x % T;
    int node = blockIdx.x * NPB + threadIdx.x / T;
    if (node >= N) return;
    int e0 = row_ptr[node], e1 = row_ptr[node + 1];
    int fo = tf * 8;
    float acc[8] = {};
    int e = e0;
    for (; e + 1 < e1; e += 2) {
        EdgeRec ea = ep[e], eb = ep[e + 1];
        U8 xa, xb2;
        xa.v  = *(const int4*)&txb[(size_t)ea.s * RS + SRC + fo];
        xb2.v = *(const int4*)&txb[(size_t)eb.s * RS + SRC + fo];
#pragma unroll
        for (int i = 0; i < 8; ++i) acc[i] += ea.w * bf2f(xa.u[i]);
#pragma unroll
        for (int i = 0; i < 8; ++i) acc[i] += eb.w * bf2f(xb2.u[i]);
    }
    if (e < e1) {
        EdgeRec ea = ep[e];
        U8 xa;
        xa.v = *(const int4*)&txb[(size_t)ea.s * RS + SRC + fo];
#pragma unroll
        for (int i = 0; i < 8; ++i) acc[i] += ea.w * bf2f(xa.u[i]);
    }
    U8 o;
    if (PASS == 1) {
#pragma unroll
        for (int i = 0; i < 8; ++i) o.u[i] = f2bf(acc[i]);
        *(int4*)&txb[(size_t)node * RS + F + fo] = o.v;
    } else {
        U8 x0;
        x0.v = *(const int4*)&txb[(size_t)node * RS + fo];
#pragma unroll
        for (int i = 0; i < 8; ++i) o.u[i] = f2bf(2.f * acc[i] - bf2f(x0.u[i]));
        *(int4*)&txb[(size_t)node * RS + 2 * F + fo] = o.v;
    }
}

// W [K x Nout] f32 -> Wt [Nout x K] bf16
__global__ void convw_kernel(const float* __restrict__ W, ushort_t* __restrict__ Wt, int K, int Nout) {
    int id = blockIdx.x * blockDim.x + threadIdx.x;
    if (id >= K * Nout) return;
    int n = id / K, k = id % K;
    Wt[id] = f2bf(W[(size_t)k * Nout + n]);
}

// ---------------- bf16 MFMA GEMM: out = relu(A @ B + bias) ----------------
// A [M x K] bf16, Bt [Nout x K] bf16, out bf16 (stride ostride) or f32.
// 128x128 tile, BK=32, global_load_lds(16B) staging, XOR-swizzled 16B slots
// (slot ^= (row>>1)&3) realized by pre-swizzling the GLOBAL source address.
// Grid: 1D, logical tile t = rowpanel*NY + col via bijective chunked XCD swizzle.
template <bool BF16OUT, int NY>
__global__ __launch_bounds__(256) void gemm_kernel(const ushort_t* __restrict__ A,
                                                   const ushort_t* __restrict__ Bt,
                                                   const float* __restrict__ bias,
                                                   void* __restrict__ outp,
                                                   int M, int K, int Nout, int ostride,
                                                   int nwg) {
    __shared__ ushort_t As[128 * 32];  // linear [row][32], 16B slot s holds global slot s^((row>>1)&3)
    __shared__ ushort_t Bs[128 * 32];
    int tid = threadIdx.x;
    // bijective chunked XCD swizzle (m204): hw id -> logical tile, 8 XCDs
    int orig = blockIdx.x;
    int q = nwg >> 3, r = nwg & 7;
    int xcd = orig & 7, m8 = orig >> 3;
    int t = (xcd < r ? xcd * (q + 1) : r * (q + 1) + (xcd - r) * q) + m8;
    int brow = (t / NY) * 128;
    int bcol = (t % NY) * 128;

    int lane = tid & 63, w = tid >> 6;
    int wr = w >> 1, wc = w & 1;
    int g = lane >> 4, lr = lane & 15;
    f32x4 acc[4][4] = {};

    // staging geometry: part p in {0,1}; lds chunk (p*4+w) covers rows [(p*4+w)*16, +16)
    // lane l -> row_in_chunk = l>>2, dest slot = l&3; global slot = (l&3) ^ ((row>>1)&3)
    int srow[2], scol[2];
#pragma unroll
    for (int p = 0; p < 2; ++p) {
        int row = (p * 4 + w) * 16 + (lane >> 2);
        srow[p] = row;
        scol[p] = ((lane & 3) ^ ((row >> 1) & 3)) * 8;
    }

    for (int kt = 0; kt < K; kt += 32) {
#pragma unroll
        for (int p = 0; p < 2; ++p) {
            int ar = brow + srow[p]; ar = ar < M ? ar : M - 1;  // clamp (stores are guarded)
            gload16(&A[(size_t)ar * K + kt + scol[p]], &As[(p * 4 + w) * 512]);
            gload16(&Bt[(size_t)(bcol + srow[p]) * K + kt + scol[p]], &Bs[(p * 4 + w) * 512]);
        }
        __syncthreads();  // compiler emits vmcnt(0) drain before barrier
        bf16x8 a[4], b[4];
#pragma unroll
        for (int m = 0; m < 4; ++m) {
            int row = wr * 64 + m * 16 + lr;
            a[m] = *(const bf16x8*)&As[row * 32 + ((g ^ ((row >> 1) & 3)) * 8)];
        }
#pragma unroll
        for (int n = 0; n < 4; ++n) {
            int row = wc * 64 + n * 16 + lr;
            b[n] = *(const bf16x8*)&Bs[row * 32 + ((g ^ ((row >> 1) & 3)) * 8)];
        }
#pragma unroll
        for (int m = 0; m < 4; ++m)
#pragma unroll
            for (int n = 0; n < 4; ++n)
                acc[m][n] = __builtin_amdgcn_mfma_f32_16x16x32_bf16(a[m], b[n], acc[m][n], 0, 0, 0);
        __syncthreads();
    }

#pragma unroll
    for (int m = 0; m < 4; ++m) {
        int grow_base = brow + wr * 64 + m * 16 + g * 4;  // C/D: col=lane&15, row=(lane>>4)*4+reg
#pragma unroll
        for (int n = 0; n < 4; ++n) {
            int gcol = bcol + wc * 64 + n * 16 + lr;
            float bv = bias[gcol];
#pragma unroll
            for (int r2 = 0; r2 < 4; ++r2) {
                int grow = grow_base + r2;
                if (grow < M) {
                    float v2 = acc[m][n][r2] + bv;
                    v2 = v2 > 0.f ? v2 : 0.f;
                    if (BF16OUT)
                        ((ushort_t*)outp)[(size_t)grow * ostride + gcol] = f2bf(v2);
                    else
                        ((float*)outp)[(size_t)grow * ostride + gcol] = v2;
                }
            }
        }
    }
}

extern "C" void kernel_launch(void* const* d_in, const int* in_sizes, int n_in,
                              void* d_out, int out_size, void* d_ws, size_t ws_size,
                              hipStream_t stream) {
    const float* v  = (const float*)d_in[0];
    const int*   ei = (const int*)d_in[1];
    const float* W1 = (const float*)d_in[2];
    const float* b1 = (const float*)d_in[3];
    const float* W2 = (const float*)d_in[4];
    const float* b2 = (const float*)d_in[5];
    const float* W3 = (const float*)d_in[6];
    const float* b3 = (const float*)d_in[7];

    const int N = in_sizes[0] / 32;
    const int E = in_sizes[1] / 2;
    const int* src = ei;
    const int* dst = ei + E;

    char* ws = (char*)d_ws;
    size_t off = 0;
    auto alloc = [&](size_t bytes) {
        off = (off + 255) & ~(size_t)255;
        char* p = ws + off;
        off += bytes;
        return p;
    };
    EdgeRec*  ep      = (EdgeRec*)alloc((size_t)E * 8);
    int*      row_ptr = (int*)alloc((size_t)(N + 1) * 4);
    int*      wofs    = (int*)alloc((size_t)N * 4);
    int*      cnt_src = (int*)alloc((size_t)N * 4);
    int*      cnt_dst = (int*)alloc((size_t)N * 4);
    float*    dinv    = (float*)alloc((size_t)N * 4);
    ushort_t* Wt      = (ushort_t*)alloc((size_t)512 * 768 * 2);
    ushort_t* txb3    = (ushort_t*)alloc((size_t)N * 768 * 2);  // [N x 768] bf16, 76.8MB
    ushort_t* txb1    = txb3;               // [N x 96] aliases txb3 (dead before gemm2)
    ushort_t* txb2    = (ushort_t*)d_out;   // [N x 384] in d_out; dead before gemm3 writes
    float*    outF    = (float*)d_out;

    // ---- graph build ----
    hipMemsetAsync(cnt_src, 0, (size_t)N * 4, stream);
    hipMemsetAsync(cnt_dst, 0, (size_t)N * 4, stream);
    count_kernel<<<(E + 255) / 256, 256, 0, stream>>>(src, dst, cnt_src, cnt_dst, E, N);
    dinv_kernel<<<(N + 255) / 256, 256, 0, stream>>>(cnt_src, dinv, N);
    scan_kernel<<<1, 1024, 0, stream>>>(cnt_dst, row_ptr, wofs, N);
    fill_kernel<<<(E + 255) / 256, 256, 0, stream>>>(src, dst, dinv, wofs, ep, E, N);

    const int mt = (N + 127) / 128;  // 391 row panels

    // ---- layer 1: 32 -> 128 ----
    convin_kernel<<<(N * 4 + 255) / 256, 256, 0, stream>>>(v, txb1, N);
    prop_kernel<32, 1><<<(N + 63) / 64, 256, 0, stream>>>(txb1, row_ptr, ep, N);
    prop_kernel<32, 2><<<(N + 63) / 64, 256, 0, stream>>>(txb1, row_ptr, ep, N);
    convw_kernel<<<(96 * 128 + 255) / 256, 256, 0, stream>>>(W1, Wt, 96, 128);
    gemm_kernel<true, 1><<<mt * 1, 256, 0, stream>>>(txb1, Wt, b1, txb2, N, 96, 128, 384, mt * 1);

    // ---- layer 2: 128 -> 256 ----
    prop_kernel<128, 1><<<(N + 15) / 16, 256, 0, stream>>>(txb2, row_ptr, ep, N);
    prop_kernel<128, 2><<<(N + 15) / 16, 256, 0, stream>>>(txb2, row_ptr, ep, N);
    convw_kernel<<<(384 * 256 + 255) / 256, 256, 0, stream>>>(W2, Wt, 384, 256);
    gemm_kernel<true, 2><<<mt * 2, 256, 0, stream>>>(txb2, Wt, b2, txb3, N, 384, 256, 768, mt * 2);

    // ---- layer 3: 256 -> 512 ----
    prop_kernel<256, 1><<<(N + 7) / 8, 256, 0, stream>>>(txb3, row_ptr, ep, N);
    prop_kernel<256, 2><<<(N + 7) / 8, 256, 0, stream>>>(txb3, row_ptr, ep, N);
    convw_kernel<<<(768 * 512 + 255) / 256, 256, 0, stream>>>(W3, Wt, 768, 512);
    gemm_kernel<false, 4><<<mt * 4, 256, 0, stream>>>(txb3, Wt, b3, outF, N, 768, 512, 512, mt * 4);
}

// Round 5
// 478.517 us; speedup vs baseline: 2.7549x; 1.2017x over previous
//
#include <hip/hip_runtime.h>
#include <hip/hip_bf16.h>

// SpectralMoleculeEncoder: 3-layer ChebConv (K=3), N=50000, E=800000, 32->128->256->512.
// R5 = R4 + hierarchical scan: the single-block scan_kernel was 110us (one CU, latency-
// bound serial loops). Replaced by blocksum -> scanblock -> scatter_scan (~8us total).
// GEMM (global_load_lds + XOR-swizzle + XCD swizzle) and bf16 prop pipeline unchanged.

typedef __bf16 bf16x8 __attribute__((ext_vector_type(8)));
typedef float f32x4 __attribute__((ext_vector_type(4)));
typedef unsigned short ushort_t;

struct EdgeRec { int s; float w; };

__device__ inline float bf2f(ushort_t u) { return __builtin_bit_cast(float, (unsigned)u << 16); }
__device__ inline ushort_t f2bf(float f) { return __builtin_bit_cast(ushort_t, (__bf16)f); }

union U8 { int4 v; ushort_t u[8]; };

__device__ inline void gload16(const ushort_t* g, ushort_t* l) {
    __builtin_amdgcn_global_load_lds(
        (const __attribute__((address_space(1))) unsigned int*)g,
        (__attribute__((address_space(3))) unsigned int*)l, 16, 0, 0);
}

// ---------------- graph build ----------------
__global__ void count_kernel(const int* __restrict__ src, const int* __restrict__ dst,
                             int* __restrict__ cnt_src, int* __restrict__ cnt_dst, int E, int N) {
    int e = blockIdx.x * blockDim.x + threadIdx.x;
    if (e >= E) return;
    int s = src[e], d = dst[e];
    if ((unsigned)s < (unsigned)N) atomicAdd(&cnt_src[s], 1);
    if ((unsigned)d < (unsigned)N) atomicAdd(&cnt_dst[d], 1);
}

__global__ void dinv_kernel(const int* __restrict__ cnt_src, float* __restrict__ dinv, int N) {
    int i = blockIdx.x * blockDim.x + threadIdx.x;
    if (i >= N) return;
    int c = cnt_src[i];
    dinv[i] = (c > 0) ? rsqrtf((float)c) : 0.0f;
}

// ---- hierarchical exclusive scan of cnt[N] -> row_ptr[N+1], wofs[N] ----
__global__ void blocksum_kernel(const int* __restrict__ cnt, int* __restrict__ bsum, int N) {
    int i = blockIdx.x * 256 + threadIdx.x;
    int v = (i < N) ? cnt[i] : 0;
#pragma unroll
    for (int off = 32; off >= 1; off >>= 1) v += __shfl_xor(v, off);
    __shared__ int ws[4];
    if ((threadIdx.x & 63) == 0) ws[threadIdx.x >> 6] = v;
    __syncthreads();
    if (threadIdx.x == 0) bsum[blockIdx.x] = ws[0] + ws[1] + ws[2] + ws[3];
}

// 1 block, 256 threads: exclusive scan of bsum[nb] (nb <= 256) -> boff[nb]
__global__ void scanblock_kernel(const int* __restrict__ bsum, int* __restrict__ boff, int nb) {
    __shared__ int s[256];
    int t = threadIdx.x;
    int v = (t < nb) ? bsum[t] : 0;
    s[t] = v;
    __syncthreads();
#pragma unroll
    for (int off = 1; off < 256; off <<= 1) {
        int u = (t >= off) ? s[t - off] : 0;
        __syncthreads();
        s[t] += u;
        __syncthreads();
    }
    if (t < nb) boff[t] = s[t] - v;  // exclusive
}

// grid covers i in [0, N]: exclusive scan within block + boff -> row_ptr, wofs
__global__ void scatter_scan_kernel(const int* __restrict__ cnt, const int* __restrict__ boff,
                                    int* __restrict__ row_ptr, int* __restrict__ wofs, int N) {
    __shared__ int s[256];
    int t = threadIdx.x;
    int i = blockIdx.x * 256 + t;
    int v = (i < N) ? cnt[i] : 0;
    s[t] = v;
    __syncthreads();
#pragma unroll
    for (int off = 1; off < 256; off <<= 1) {
        int u = (t >= off) ? s[t - off] : 0;
        __syncthreads();
        s[t] += u;
        __syncthreads();
    }
    int run = boff[blockIdx.x] + s[t] - v;  // exclusive prefix at i
    if (i < N) { row_ptr[i] = run; wofs[i] = run; }
    else if (i == N) row_ptr[N] = run;  // total
}

__global__ void fill_kernel(const int* __restrict__ src, const int* __restrict__ dst,
                            const float* __restrict__ dinv, int* __restrict__ wofs,
                            EdgeRec* __restrict__ ep, int E, int N) {
    int e = blockIdx.x * blockDim.x + threadIdx.x;
    if (e >= E) return;
    int s = src[e], d = dst[e];
    if ((unsigned)s >= (unsigned)N || (unsigned)d >= (unsigned)N) return;
    int pos = atomicAdd(&wofs[d], 1);
    EdgeRec er; er.s = s; er.w = -dinv[s] * dinv[d];
    ep[pos] = er;
}

// v [N,32] f32 -> txb1 slice0 bf16 (row stride 96)
__global__ void convin_kernel(const float* __restrict__ v, ushort_t* __restrict__ txb, int N) {
    int id = blockIdx.x * blockDim.x + threadIdx.x;
    if (id >= N * 4) return;
    int node = id >> 2, c = (id & 3) << 3;
    const float* p = &v[(size_t)node * 32 + c];
    U8 o;
#pragma unroll
    for (int i = 0; i < 8; ++i) o.u[i] = f2bf(p[i]);
    *(int4*)&txb[(size_t)node * 96 + c] = o.v;
}

// ---------------- propagation (CSR gather, bf16, 16B/lane) ----------------
template <int F, int PASS>
__global__ __launch_bounds__(256) void prop_kernel(ushort_t* __restrict__ txb,
                                                   const int* __restrict__ row_ptr,
                                                   const EdgeRec* __restrict__ ep, int N) {
    constexpr int T = F / 8;        // lanes per node
    constexpr int NPB = 256 / T;    // nodes per block
    constexpr int RS = 3 * F;       // txb row stride
    constexpr int SRC = (PASS == 1) ? 0 : F;
    int tf = threadIdx.x % T;
    int node = blockIdx.x * NPB + threadIdx.x / T;
    if (node >= N) return;
    int e0 = row_ptr[node], e1 = row_ptr[node + 1];
    int fo = tf * 8;
    float acc[8] = {};
    int e = e0;
    for (; e + 1 < e1; e += 2) {
        EdgeRec ea = ep[e], eb = ep[e + 1];
        U8 xa, xb2;
        xa.v  = *(const int4*)&txb[(size_t)ea.s * RS + SRC + fo];
        xb2.v = *(const int4*)&txb[(size_t)eb.s * RS + SRC + fo];
#pragma unroll
        for (int i = 0; i < 8; ++i) acc[i] += ea.w * bf2f(xa.u[i]);
#pragma unroll
        for (int i = 0; i < 8; ++i) acc[i] += eb.w * bf2f(xb2.u[i]);
    }
    if (e < e1) {
        EdgeRec ea = ep[e];
        U8 xa;
        xa.v = *(const int4*)&txb[(size_t)ea.s * RS + SRC + fo];
#pragma unroll
        for (int i = 0; i < 8; ++i) acc[i] += ea.w * bf2f(xa.u[i]);
    }
    U8 o;
    if (PASS == 1) {
#pragma unroll
        for (int i = 0; i < 8; ++i) o.u[i] = f2bf(acc[i]);
        *(int4*)&txb[(size_t)node * RS + F + fo] = o.v;
    } else {
        U8 x0;
        x0.v = *(const int4*)&txb[(size_t)node * RS + fo];
#pragma unroll
        for (int i = 0; i < 8; ++i) o.u[i] = f2bf(2.f * acc[i] - bf2f(x0.u[i]));
        *(int4*)&txb[(size_t)node * RS + 2 * F + fo] = o.v;
    }
}

// W [K x Nout] f32 -> Wt [Nout x K] bf16
__global__ void convw_kernel(const float* __restrict__ W, ushort_t* __restrict__ Wt, int K, int Nout) {
    int id = blockIdx.x * blockDim.x + threadIdx.x;
    if (id >= K * Nout) return;
    int n = id / K, k = id % K;
    Wt[id] = f2bf(W[(size_t)k * Nout + n]);
}

// ---------------- bf16 MFMA GEMM: out = relu(A @ B + bias) ----------------
// 128x128 tile, BK=32, global_load_lds(16B) staging, XOR-swizzled 16B slots
// (slot ^= (row>>1)&3) realized by pre-swizzling the GLOBAL source address.
// Grid: 1D, logical tile t = rowpanel*NY + col via bijective chunked XCD swizzle.
template <bool BF16OUT, int NY>
__global__ __launch_bounds__(256) void gemm_kernel(const ushort_t* __restrict__ A,
                                                   const ushort_t* __restrict__ Bt,
                                                   const float* __restrict__ bias,
                                                   void* __restrict__ outp,
                                                   int M, int K, int Nout, int ostride,
                                                   int nwg) {
    __shared__ ushort_t As[128 * 32];
    __shared__ ushort_t Bs[128 * 32];
    int tid = threadIdx.x;
    int orig = blockIdx.x;
    int q = nwg >> 3, r = nwg & 7;
    int xcd = orig & 7, m8 = orig >> 3;
    int t = (xcd < r ? xcd * (q + 1) : r * (q + 1) + (xcd - r) * q) + m8;
    int brow = (t / NY) * 128;
    int bcol = (t % NY) * 128;

    int lane = tid & 63, w = tid >> 6;
    int wr = w >> 1, wc = w & 1;
    int g = lane >> 4, lr = lane & 15;
    f32x4 acc[4][4] = {};

    int srow[2], scol[2];
#pragma unroll
    for (int p = 0; p < 2; ++p) {
        int row = (p * 4 + w) * 16 + (lane >> 2);
        srow[p] = row;
        scol[p] = ((lane & 3) ^ ((row >> 1) & 3)) * 8;
    }

    for (int kt = 0; kt < K; kt += 32) {
#pragma unroll
        for (int p = 0; p < 2; ++p) {
            int ar = brow + srow[p]; ar = ar < M ? ar : M - 1;
            gload16(&A[(size_t)ar * K + kt + scol[p]], &As[(p * 4 + w) * 512]);
            gload16(&Bt[(size_t)(bcol + srow[p]) * K + kt + scol[p]], &Bs[(p * 4 + w) * 512]);
        }
        __syncthreads();
        bf16x8 a[4], b[4];
#pragma unroll
        for (int m = 0; m < 4; ++m) {
            int row = wr * 64 + m * 16 + lr;
            a[m] = *(const bf16x8*)&As[row * 32 + ((g ^ ((row >> 1) & 3)) * 8)];
        }
#pragma unroll
        for (int n = 0; n < 4; ++n) {
            int row = wc * 64 + n * 16 + lr;
            b[n] = *(const bf16x8*)&Bs[row * 32 + ((g ^ ((row >> 1) & 3)) * 8)];
        }
#pragma unroll
        for (int m = 0; m < 4; ++m)
#pragma unroll
            for (int n = 0; n < 4; ++n)
                acc[m][n] = __builtin_amdgcn_mfma_f32_16x16x32_bf16(a[m], b[n], acc[m][n], 0, 0, 0);
        __syncthreads();
    }

#pragma unroll
    for (int m = 0; m < 4; ++m) {
        int grow_base = brow + wr * 64 + m * 16 + g * 4;
#pragma unroll
        for (int n = 0; n < 4; ++n) {
            int gcol = bcol + wc * 64 + n * 16 + lr;
            float bv = bias[gcol];
#pragma unroll
            for (int r2 = 0; r2 < 4; ++r2) {
                int grow = grow_base + r2;
                if (grow < M) {
                    float v2 = acc[m][n][r2] + bv;
                    v2 = v2 > 0.f ? v2 : 0.f;
                    if (BF16OUT)
                        ((ushort_t*)outp)[(size_t)grow * ostride + gcol] = f2bf(v2);
                    else
                        ((float*)outp)[(size_t)grow * ostride + gcol] = v2;
                }
            }
        }
    }
}

extern "C" void kernel_launch(void* const* d_in, const int* in_sizes, int n_in,
                              void* d_out, int out_size, void* d_ws, size_t ws_size,
                              hipStream_t stream) {
    const float* v  = (const float*)d_in[0];
    const int*   ei = (const int*)d_in[1];
    const float* W1 = (const float*)d_in[2];
    const float* b1 = (const float*)d_in[3];
    const float* W2 = (const float*)d_in[4];
    const float* b2 = (const float*)d_in[5];
    const float* W3 = (const float*)d_in[6];
    const float* b3 = (const float*)d_in[7];

    const int N = in_sizes[0] / 32;
    const int E = in_sizes[1] / 2;
    const int* src = ei;
    const int* dst = ei + E;

    char* ws = (char*)d_ws;
    size_t off = 0;
    auto alloc = [&](size_t bytes) {
        off = (off + 255) & ~(size_t)255;
        char* p = ws + off;
        off += bytes;
        return p;
    };
    EdgeRec*  ep      = (EdgeRec*)alloc((size_t)E * 8);
    int*      row_ptr = (int*)alloc((size_t)(N + 1) * 4);
    int*      wofs    = (int*)alloc((size_t)N * 4);
    int*      cnt_src = (int*)alloc((size_t)N * 4);
    int*      cnt_dst = (int*)alloc((size_t)N * 4);
    float*    dinv    = (float*)alloc((size_t)N * 4);
    int*      bsum    = (int*)alloc((size_t)256 * 4);
    int*      boff    = (int*)alloc((size_t)256 * 4);
    ushort_t* Wt      = (ushort_t*)alloc((size_t)512 * 768 * 2);
    ushort_t* txb3    = (ushort_t*)alloc((size_t)N * 768 * 2);  // [N x 768] bf16, 76.8MB
    ushort_t* txb1    = txb3;               // [N x 96] aliases txb3 (dead before gemm2)
    ushort_t* txb2    = (ushort_t*)d_out;   // [N x 384] in d_out; dead before gemm3 writes
    float*    outF    = (float*)d_out;

    const int nb = (N + 255) / 256;  // 196 scan blocks (<=256 for scanblock)

    // ---- graph build ----
    hipMemsetAsync(cnt_src, 0, (size_t)N * 4, stream);
    hipMemsetAsync(cnt_dst, 0, (size_t)N * 4, stream);
    count_kernel<<<(E + 255) / 256, 256, 0, stream>>>(src, dst, cnt_src, cnt_dst, E, N);
    dinv_kernel<<<(N + 255) / 256, 256, 0, stream>>>(cnt_src, dinv, N);
    blocksum_kernel<<<nb, 256, 0, stream>>>(cnt_dst, bsum, N);
    scanblock_kernel<<<1, 256, 0, stream>>>(bsum, boff, nb);
    scatter_scan_kernel<<<nb, 256, 0, stream>>>(cnt_dst, boff, row_ptr, wofs, N);
    fill_kernel<<<(E + 255) / 256, 256, 0, stream>>>(src, dst, dinv, wofs, ep, E, N);

    const int mt = (N + 127) / 128;  // 391 row panels

    // ---- layer 1: 32 -> 128 ----
    convin_kernel<<<(N * 4 + 255) / 256, 256, 0, stream>>>(v, txb1, N);
    prop_kernel<32, 1><<<(N + 63) / 64, 256, 0, stream>>>(txb1, row_ptr, ep, N);
    prop_kernel<32, 2><<<(N + 63) / 64, 256, 0, stream>>>(txb1, row_ptr, ep, N);
    convw_kernel<<<(96 * 128 + 255) / 256, 256, 0, stream>>>(W1, Wt, 96, 128);
    gemm_kernel<true, 1><<<mt * 1, 256, 0, stream>>>(txb1, Wt, b1, txb2, N, 96, 128, 384, mt * 1);

    // ---- layer 2: 128 -> 256 ----
    prop_kernel<128, 1><<<(N + 15) / 16, 256, 0, stream>>>(txb2, row_ptr, ep, N);
    prop_kernel<128, 2><<<(N + 15) / 16, 256, 0, stream>>>(txb2, row_ptr, ep, N);
    convw_kernel<<<(384 * 256 + 255) / 256, 256, 0, stream>>>(W2, Wt, 384, 256);
    gemm_kernel<true, 2><<<mt * 2, 256, 0, stream>>>(txb2, Wt, b2, txb3, N, 384, 256, 768, mt * 2);

    // ---- layer 3: 256 -> 512 ----
    prop_kernel<256, 1><<<(N + 7) / 8, 256, 0, stream>>>(txb3, row_ptr, ep, N);
    prop_kernel<256, 2><<<(N + 7) / 8, 256, 0, stream>>>(txb3, row_ptr, ep, N);
    convw_kernel<<<(768 * 512 + 255) / 256, 256, 0, stream>>>(W3, Wt, 768, 512);
    gemm_kernel<false, 4><<<mt * 4, 256, 0, stream>>>(txb3, Wt, b3, outF, N, 768, 512, 512, mt * 4);
}

// Round 6
// 465.971 us; speedup vs baseline: 2.8290x; 1.0269x over previous
//
#include <hip/hip_runtime.h>
#include <hip/hip_bf16.h>

// SpectralMoleculeEncoder: 3-layer ChebConv (K=3), N=50000, E=800000, 32->128->256->512.
// R6 = R5 + (a) GEMM double-buffered 2-phase pipeline: STAGE(next) issued before
// compute(cur), ONE __syncthreads per K-iter (its implicit vmcnt(0) drain is the wait
// for next tile) -> staging latency hides under MFMA; (b) prop gather unroll x4 for MLP.

typedef __bf16 bf16x8 __attribute__((ext_vector_type(8)));
typedef float f32x4 __attribute__((ext_vector_type(4)));
typedef unsigned short ushort_t;

struct EdgeRec { int s; float w; };

__device__ inline float bf2f(ushort_t u) { return __builtin_bit_cast(float, (unsigned)u << 16); }
__device__ inline ushort_t f2bf(float f) { return __builtin_bit_cast(ushort_t, (__bf16)f); }

union U8 { int4 v; ushort_t u[8]; };

__device__ inline void gload16(const ushort_t* g, ushort_t* l) {
    __builtin_amdgcn_global_load_lds(
        (const __attribute__((address_space(1))) unsigned int*)g,
        (__attribute__((address_space(3))) unsigned int*)l, 16, 0, 0);
}

// ---------------- graph build ----------------
__global__ void count_kernel(const int* __restrict__ src, const int* __restrict__ dst,
                             int* __restrict__ cnt_src, int* __restrict__ cnt_dst, int E, int N) {
    int e = blockIdx.x * blockDim.x + threadIdx.x;
    if (e >= E) return;
    int s = src[e], d = dst[e];
    if ((unsigned)s < (unsigned)N) atomicAdd(&cnt_src[s], 1);
    if ((unsigned)d < (unsigned)N) atomicAdd(&cnt_dst[d], 1);
}

__global__ void dinv_kernel(const int* __restrict__ cnt_src, float* __restrict__ dinv, int N) {
    int i = blockIdx.x * blockDim.x + threadIdx.x;
    if (i >= N) return;
    int c = cnt_src[i];
    dinv[i] = (c > 0) ? rsqrtf((float)c) : 0.0f;
}

// ---- hierarchical exclusive scan of cnt[N] -> row_ptr[N+1], wofs[N] ----
__global__ void blocksum_kernel(const int* __restrict__ cnt, int* __restrict__ bsum, int N) {
    int i = blockIdx.x * 256 + threadIdx.x;
    int v = (i < N) ? cnt[i] : 0;
#pragma unroll
    for (int off = 32; off >= 1; off >>= 1) v += __shfl_xor(v, off);
    __shared__ int ws[4];
    if ((threadIdx.x & 63) == 0) ws[threadIdx.x >> 6] = v;
    __syncthreads();
    if (threadIdx.x == 0) bsum[blockIdx.x] = ws[0] + ws[1] + ws[2] + ws[3];
}

__global__ void scanblock_kernel(const int* __restrict__ bsum, int* __restrict__ boff, int nb) {
    __shared__ int s[256];
    int t = threadIdx.x;
    int v = (t < nb) ? bsum[t] : 0;
    s[t] = v;
    __syncthreads();
#pragma unroll
    for (int off = 1; off < 256; off <<= 1) {
        int u = (t >= off) ? s[t - off] : 0;
        __syncthreads();
        s[t] += u;
        __syncthreads();
    }
    if (t < nb) boff[t] = s[t] - v;  // exclusive
}

__global__ void scatter_scan_kernel(const int* __restrict__ cnt, const int* __restrict__ boff,
                                    int* __restrict__ row_ptr, int* __restrict__ wofs, int N) {
    __shared__ int s[256];
    int t = threadIdx.x;
    int i = blockIdx.x * 256 + t;
    int v = (i < N) ? cnt[i] : 0;
    s[t] = v;
    __syncthreads();
#pragma unroll
    for (int off = 1; off < 256; off <<= 1) {
        int u = (t >= off) ? s[t - off] : 0;
        __syncthreads();
        s[t] += u;
        __syncthreads();
    }
    int run = boff[blockIdx.x] + s[t] - v;
    if (i < N) { row_ptr[i] = run; wofs[i] = run; }
    else if (i == N) row_ptr[N] = run;
}

__global__ void fill_kernel(const int* __restrict__ src, const int* __restrict__ dst,
                            const float* __restrict__ dinv, int* __restrict__ wofs,
                            EdgeRec* __restrict__ ep, int E, int N) {
    int e = blockIdx.x * blockDim.x + threadIdx.x;
    if (e >= E) return;
    int s = src[e], d = dst[e];
    if ((unsigned)s >= (unsigned)N || (unsigned)d >= (unsigned)N) return;
    int pos = atomicAdd(&wofs[d], 1);
    EdgeRec er; er.s = s; er.w = -dinv[s] * dinv[d];
    ep[pos] = er;
}

// v [N,32] f32 -> txb1 slice0 bf16 (row stride 96)
__global__ void convin_kernel(const float* __restrict__ v, ushort_t* __restrict__ txb, int N) {
    int id = blockIdx.x * blockDim.x + threadIdx.x;
    if (id >= N * 4) return;
    int node = id >> 2, c = (id & 3) << 3;
    const float* p = &v[(size_t)node * 32 + c];
    U8 o;
#pragma unroll
    for (int i = 0; i < 8; ++i) o.u[i] = f2bf(p[i]);
    *(int4*)&txb[(size_t)node * 96 + c] = o.v;
}

// ---------------- propagation (CSR gather, bf16, 16B/lane, unroll x4) ----------------
template <int F, int PASS>
__global__ __launch_bounds__(256) void prop_kernel(ushort_t* __restrict__ txb,
                                                   const int* __restrict__ row_ptr,
                                                   const EdgeRec* __restrict__ ep, int N) {
    constexpr int T = F / 8;        // lanes per node
    constexpr int NPB = 256 / T;    // nodes per block
    constexpr int RS = 3 * F;       // txb row stride
    constexpr int SRC = (PASS == 1) ? 0 : F;
    int tf = threadIdx.x % T;
    int node = blockIdx.x * NPB + threadIdx.x / T;
    if (node >= N) return;
    int e0 = row_ptr[node], e1 = row_ptr[node + 1];
    int fo = tf * 8;
    float acc[8] = {};
    int e = e0;
    for (; e + 3 < e1; e += 4) {
        EdgeRec er[4];
        U8 x[4];
#pragma unroll
        for (int j = 0; j < 4; ++j) er[j] = ep[e + j];
#pragma unroll
        for (int j = 0; j < 4; ++j)
            x[j].v = *(const int4*)&txb[(size_t)er[j].s * RS + SRC + fo];
#pragma unroll
        for (int j = 0; j < 4; ++j)
#pragma unroll
            for (int i = 0; i < 8; ++i) acc[i] += er[j].w * bf2f(x[j].u[i]);
    }
    for (; e < e1; ++e) {
        EdgeRec ea = ep[e];
        U8 xa;
        xa.v = *(const int4*)&txb[(size_t)ea.s * RS + SRC + fo];
#pragma unroll
        for (int i = 0; i < 8; ++i) acc[i] += ea.w * bf2f(xa.u[i]);
    }
    U8 o;
    if (PASS == 1) {
#pragma unroll
        for (int i = 0; i < 8; ++i) o.u[i] = f2bf(acc[i]);
        *(int4*)&txb[(size_t)node * RS + F + fo] = o.v;
    } else {
        U8 x0;
        x0.v = *(const int4*)&txb[(size_t)node * RS + fo];
#pragma unroll
        for (int i = 0; i < 8; ++i) o.u[i] = f2bf(2.f * acc[i] - bf2f(x0.u[i]));
        *(int4*)&txb[(size_t)node * RS + 2 * F + fo] = o.v;
    }
}

// W [K x Nout] f32 -> Wt [Nout x K] bf16
__global__ void convw_kernel(const float* __restrict__ W, ushort_t* __restrict__ Wt, int K, int Nout) {
    int id = blockIdx.x * blockDim.x + threadIdx.x;
    if (id >= K * Nout) return;
    int n = id / K, k = id % K;
    Wt[id] = f2bf(W[(size_t)k * Nout + n]);
}

// ---------------- bf16 MFMA GEMM: out = relu(A @ B + bias) ----------------
// 128x128 tile, BK=32, double-buffered 2-phase pipeline: STAGE(next buf) issued before
// ds_read+MFMA of cur buf; single __syncthreads per K-iter (compiler's vmcnt(0)+lgkmcnt(0)
// drain before s_barrier IS the wait for the prefetched tile). XOR-swizzled 16B slots via
// pre-swizzled global source; bijective chunked XCD swizzle, tile t = rowpanel*NY + col.
template <bool BF16OUT, int NY>
__global__ __launch_bounds__(256) void gemm_kernel(const ushort_t* __restrict__ A,
                                                   const ushort_t* __restrict__ Bt,
                                                   const float* __restrict__ bias,
                                                   void* __restrict__ outp,
                                                   int M, int K, int Nout, int ostride,
                                                   int nwg) {
    __shared__ ushort_t As[2][128 * 32];
    __shared__ ushort_t Bs[2][128 * 32];
    int tid = threadIdx.x;
    int orig = blockIdx.x;
    int q = nwg >> 3, r = nwg & 7;
    int xcd = orig & 7, m8 = orig >> 3;
    int t = (xcd < r ? xcd * (q + 1) : r * (q + 1) + (xcd - r) * q) + m8;
    int brow = (t / NY) * 128;
    int bcol = (t % NY) * 128;

    int lane = tid & 63, w = tid >> 6;
    int wr = w >> 1, wc = w & 1;
    int g = lane >> 4, lr = lane & 15;
    f32x4 acc[4][4] = {};

    int srow[2], scol[2];
#pragma unroll
    for (int p = 0; p < 2; ++p) {
        int row = (p * 4 + w) * 16 + (lane >> 2);
        srow[p] = row;
        scol[p] = ((lane & 3) ^ ((row >> 1) & 3)) * 8;
    }

    // precompute per-lane global row bases (A row clamped; stores guarded by M later)
    size_t abase[2], bbase[2];
#pragma unroll
    for (int p = 0; p < 2; ++p) {
        int ar = brow + srow[p]; ar = ar < M ? ar : M - 1;
        abase[p] = (size_t)ar * K + scol[p];
        bbase[p] = (size_t)(bcol + srow[p]) * K + scol[p];
    }

    auto stage = [&](int buf, int kt) {
#pragma unroll
        for (int p = 0; p < 2; ++p) {
            gload16(&A[abase[p] + kt], &As[buf][(p * 4 + w) * 512]);
            gload16(&Bt[bbase[p] + kt], &Bs[buf][(p * 4 + w) * 512]);
        }
    };

    // frag LDS offsets (swizzled read side)
    int aoff[4], boff4[4];
#pragma unroll
    for (int m = 0; m < 4; ++m) {
        int row = wr * 64 + m * 16 + lr;
        aoff[m] = row * 32 + ((g ^ ((row >> 1) & 3)) * 8);
    }
#pragma unroll
    for (int n = 0; n < 4; ++n) {
        int row = wc * 64 + n * 16 + lr;
        boff4[n] = row * 32 + ((g ^ ((row >> 1) & 3)) * 8);
    }

    stage(0, 0);
    __syncthreads();  // drain vmcnt(0): buf0 ready
    int cur = 0;
    for (int kt = 0; kt < K; kt += 32) {
        if (kt + 32 < K) stage(cur ^ 1, kt + 32);  // prefetch next tile, latency under MFMA
        bf16x8 a[4], b[4];
#pragma unroll
        for (int m = 0; m < 4; ++m) a[m] = *(const bf16x8*)&As[cur][aoff[m]];
#pragma unroll
        for (int n = 0; n < 4; ++n) b[n] = *(const bf16x8*)&Bs[cur][boff4[n]];
#pragma unroll
        for (int m = 0; m < 4; ++m)
#pragma unroll
            for (int n = 0; n < 4; ++n)
                acc[m][n] = __builtin_amdgcn_mfma_f32_16x16x32_bf16(a[m], b[n], acc[m][n], 0, 0, 0);
        __syncthreads();  // drain vmcnt(0): next buf ready; also guards buf reuse
        cur ^= 1;
    }

#pragma unroll
    for (int m = 0; m < 4; ++m) {
        int grow_base = brow + wr * 64 + m * 16 + g * 4;
#pragma unroll
        for (int n = 0; n < 4; ++n) {
            int gcol = bcol + wc * 64 + n * 16 + lr;
            float bv = bias[gcol];
#pragma unroll
            for (int r2 = 0; r2 < 4; ++r2) {
                int grow = grow_base + r2;
                if (grow < M) {
                    float v2 = acc[m][n][r2] + bv;
                    v2 = v2 > 0.f ? v2 : 0.f;
                    if (BF16OUT)
                        ((ushort_t*)outp)[(size_t)grow * ostride + gcol] = f2bf(v2);
                    else
                        ((float*)outp)[(size_t)grow * ostride + gcol] = v2;
                }
            }
        }
    }
}

extern "C" void kernel_launch(void* const* d_in, const int* in_sizes, int n_in,
                              void* d_out, int out_size, void* d_ws, size_t ws_size,
                              hipStream_t stream) {
    const float* v  = (const float*)d_in[0];
    const int*   ei = (const int*)d_in[1];
    const float* W1 = (const float*)d_in[2];
    const float* b1 = (const float*)d_in[3];
    const float* W2 = (const float*)d_in[4];
    const float* b2 = (const float*)d_in[5];
    const float* W3 = (const float*)d_in[6];
    const float* b3 = (const float*)d_in[7];

    const int N = in_sizes[0] / 32;
    const int E = in_sizes[1] / 2;
    const int* src = ei;
    const int* dst = ei + E;

    char* ws = (char*)d_ws;
    size_t off = 0;
    auto alloc = [&](size_t bytes) {
        off = (off + 255) & ~(size_t)255;
        char* p = ws + off;
        off += bytes;
        return p;
    };
    EdgeRec*  ep      = (EdgeRec*)alloc((size_t)E * 8);
    int*      row_ptr = (int*)alloc((size_t)(N + 1) * 4);
    int*      wofs    = (int*)alloc((size_t)N * 4);
    int*      cnt_src = (int*)alloc((size_t)N * 4);
    int*      cnt_dst = (int*)alloc((size_t)N * 4);
    float*    dinv    = (float*)alloc((size_t)N * 4);
    int*      bsum    = (int*)alloc((size_t)256 * 4);
    int*      boff    = (int*)alloc((size_t)256 * 4);
    ushort_t* Wt      = (ushort_t*)alloc((size_t)512 * 768 * 2);
    ushort_t* txb3    = (ushort_t*)alloc((size_t)N * 768 * 2);  // [N x 768] bf16, 76.8MB
    ushort_t* txb1    = txb3;               // [N x 96] aliases txb3 (dead before gemm2)
    ushort_t* txb2    = (ushort_t*)d_out;   // [N x 384] in d_out; dead before gemm3 writes
    float*    outF    = (float*)d_out;

    const int nb = (N + 255) / 256;

    // ---- graph build ----
    hipMemsetAsync(cnt_src, 0, (size_t)N * 4, stream);
    hipMemsetAsync(cnt_dst, 0, (size_t)N * 4, stream);
    count_kernel<<<(E + 255) / 256, 256, 0, stream>>>(src, dst, cnt_src, cnt_dst, E, N);
    dinv_kernel<<<(N + 255) / 256, 256, 0, stream>>>(cnt_src, dinv, N);
    blocksum_kernel<<<nb, 256, 0, stream>>>(cnt_dst, bsum, N);
    scanblock_kernel<<<1, 256, 0, stream>>>(bsum, boff, nb);
    scatter_scan_kernel<<<nb, 256, 0, stream>>>(cnt_dst, boff, row_ptr, wofs, N);
    fill_kernel<<<(E + 255) / 256, 256, 0, stream>>>(src, dst, dinv, wofs, ep, E, N);

    const int mt = (N + 127) / 128;  // 391 row panels

    // ---- layer 1: 32 -> 128 ----
    convin_kernel<<<(N * 4 + 255) / 256, 256, 0, stream>>>(v, txb1, N);
    prop_kernel<32, 1><<<(N + 63) / 64, 256, 0, stream>>>(txb1, row_ptr, ep, N);
    prop_kernel<32, 2><<<(N + 63) / 64, 256, 0, stream>>>(txb1, row_ptr, ep, N);
    convw_kernel<<<(96 * 128 + 255) / 256, 256, 0, stream>>>(W1, Wt, 96, 128);
    gemm_kernel<true, 1><<<mt * 1, 256, 0, stream>>>(txb1, Wt, b1, txb2, N, 96, 128, 384, mt * 1);

    // ---- layer 2: 128 -> 256 ----
    prop_kernel<128, 1><<<(N + 15) / 16, 256, 0, stream>>>(txb2, row_ptr, ep, N);
    prop_kernel<128, 2><<<(N + 15) / 16, 256, 0, stream>>>(txb2, row_ptr, ep, N);
    convw_kernel<<<(384 * 256 + 255) / 256, 256, 0, stream>>>(W2, Wt, 384, 256);
    gemm_kernel<true, 2><<<mt * 2, 256, 0, stream>>>(txb2, Wt, b2, txb3, N, 384, 256, 768, mt * 2);

    // ---- layer 3: 256 -> 512 ----
    prop_kernel<256, 1><<<(N + 7) / 8, 256, 0, stream>>>(txb3, row_ptr, ep, N);
    prop_kernel<256, 2><<<(N + 7) / 8, 256, 0, stream>>>(txb3, row_ptr, ep, N);
    convw_kernel<<<(768 * 512 + 255) / 256, 256, 0, stream>>>(W3, Wt, 768, 512);
    gemm_kernel<false, 4><<<mt * 4, 256, 0, stream>>>(txb3, Wt, b3, outF, N, 768, 512, 512, mt * 4);
}

// Round 7
// 453.553 us; speedup vs baseline: 2.9065x; 1.0274x over previous
//
#include <hip/hip_runtime.h>
#include <hip/hip_bf16.h>

// SpectralMoleculeEncoder: 3-layer ChebConv (K=3), N=50000, E=800000, 32->128->256->512.
// R7 = R6 + T4 counted-vmcnt pipeline in GEMM: raw s_barrier + s_waitcnt vmcnt(4)
// (keep next-tile's 4 gload_lds in flight across the barrier) instead of __syncthreads'
// vmcnt(0) drain which was waiting on the prefetch itself. Two bare barriers per iter.
// Plus __launch_bounds__(256,3) to target 3 blocks/CU.

typedef __bf16 bf16x8 __attribute__((ext_vector_type(8)));
typedef float f32x4 __attribute__((ext_vector_type(4)));
typedef unsigned short ushort_t;

struct EdgeRec { int s; float w; };

__device__ inline float bf2f(ushort_t u) { return __builtin_bit_cast(float, (unsigned)u << 16); }
__device__ inline ushort_t f2bf(float f) { return __builtin_bit_cast(ushort_t, (__bf16)f); }

union U8 { int4 v; ushort_t u[8]; };

__device__ inline void gload16(const ushort_t* g, ushort_t* l) {
    __builtin_amdgcn_global_load_lds(
        (const __attribute__((address_space(1))) unsigned int*)g,
        (__attribute__((address_space(3))) unsigned int*)l, 16, 0, 0);
}

// ---------------- graph build ----------------
__global__ void count_kernel(const int* __restrict__ src, const int* __restrict__ dst,
                             int* __restrict__ cnt_src, int* __restrict__ cnt_dst, int E, int N) {
    int e = blockIdx.x * blockDim.x + threadIdx.x;
    if (e >= E) return;
    int s = src[e], d = dst[e];
    if ((unsigned)s < (unsigned)N) atomicAdd(&cnt_src[s], 1);
    if ((unsigned)d < (unsigned)N) atomicAdd(&cnt_dst[d], 1);
}

__global__ void dinv_kernel(const int* __restrict__ cnt_src, float* __restrict__ dinv, int N) {
    int i = blockIdx.x * blockDim.x + threadIdx.x;
    if (i >= N) return;
    int c = cnt_src[i];
    dinv[i] = (c > 0) ? rsqrtf((float)c) : 0.0f;
}

// ---- hierarchical exclusive scan of cnt[N] -> row_ptr[N+1], wofs[N] ----
__global__ void blocksum_kernel(const int* __restrict__ cnt, int* __restrict__ bsum, int N) {
    int i = blockIdx.x * 256 + threadIdx.x;
    int v = (i < N) ? cnt[i] : 0;
#pragma unroll
    for (int off = 32; off >= 1; off >>= 1) v += __shfl_xor(v, off);
    __shared__ int ws[4];
    if ((threadIdx.x & 63) == 0) ws[threadIdx.x >> 6] = v;
    __syncthreads();
    if (threadIdx.x == 0) bsum[blockIdx.x] = ws[0] + ws[1] + ws[2] + ws[3];
}

__global__ void scanblock_kernel(const int* __restrict__ bsum, int* __restrict__ boff, int nb) {
    __shared__ int s[256];
    int t = threadIdx.x;
    int v = (t < nb) ? bsum[t] : 0;
    s[t] = v;
    __syncthreads();
#pragma unroll
    for (int off = 1; off < 256; off <<= 1) {
        int u = (t >= off) ? s[t - off] : 0;
        __syncthreads();
        s[t] += u;
        __syncthreads();
    }
    if (t < nb) boff[t] = s[t] - v;  // exclusive
}

__global__ void scatter_scan_kernel(const int* __restrict__ cnt, const int* __restrict__ boff,
                                    int* __restrict__ row_ptr, int* __restrict__ wofs, int N) {
    __shared__ int s[256];
    int t = threadIdx.x;
    int i = blockIdx.x * 256 + t;
    int v = (i < N) ? cnt[i] : 0;
    s[t] = v;
    __syncthreads();
#pragma unroll
    for (int off = 1; off < 256; off <<= 1) {
        int u = (t >= off) ? s[t - off] : 0;
        __syncthreads();
        s[t] += u;
        __syncthreads();
    }
    int run = boff[blockIdx.x] + s[t] - v;
    if (i < N) { row_ptr[i] = run; wofs[i] = run; }
    else if (i == N) row_ptr[N] = run;
}

__global__ void fill_kernel(const int* __restrict__ src, const int* __restrict__ dst,
                            const float* __restrict__ dinv, int* __restrict__ wofs,
                            EdgeRec* __restrict__ ep, int E, int N) {
    int e = blockIdx.x * blockDim.x + threadIdx.x;
    if (e >= E) return;
    int s = src[e], d = dst[e];
    if ((unsigned)s >= (unsigned)N || (unsigned)d >= (unsigned)N) return;
    int pos = atomicAdd(&wofs[d], 1);
    EdgeRec er; er.s = s; er.w = -dinv[s] * dinv[d];
    ep[pos] = er;
}

// v [N,32] f32 -> txb1 slice0 bf16 (row stride 96)
__global__ void convin_kernel(const float* __restrict__ v, ushort_t* __restrict__ txb, int N) {
    int id = blockIdx.x * blockDim.x + threadIdx.x;
    if (id >= N * 4) return;
    int node = id >> 2, c = (id & 3) << 3;
    const float* p = &v[(size_t)node * 32 + c];
    U8 o;
#pragma unroll
    for (int i = 0; i < 8; ++i) o.u[i] = f2bf(p[i]);
    *(int4*)&txb[(size_t)node * 96 + c] = o.v;
}

// ---------------- propagation (CSR gather, bf16, 16B/lane, unroll x4) ----------------
template <int F, int PASS>
__global__ __launch_bounds__(256) void prop_kernel(ushort_t* __restrict__ txb,
                                                   const int* __restrict__ row_ptr,
                                                   const EdgeRec* __restrict__ ep, int N) {
    constexpr int T = F / 8;        // lanes per node
    constexpr int NPB = 256 / T;    // nodes per block
    constexpr int RS = 3 * F;       // txb row stride
    constexpr int SRC = (PASS == 1) ? 0 : F;
    int tf = threadIdx.x % T;
    int node = blockIdx.x * NPB + threadIdx.x / T;
    if (node >= N) return;
    int e0 = row_ptr[node], e1 = row_ptr[node + 1];
    int fo = tf * 8;
    float acc[8] = {};
    int e = e0;
    for (; e + 3 < e1; e += 4) {
        EdgeRec er[4];
        U8 x[4];
#pragma unroll
        for (int j = 0; j < 4; ++j) er[j] = ep[e + j];
#pragma unroll
        for (int j = 0; j < 4; ++j)
            x[j].v = *(const int4*)&txb[(size_t)er[j].s * RS + SRC + fo];
#pragma unroll
        for (int j = 0; j < 4; ++j)
#pragma unroll
            for (int i = 0; i < 8; ++i) acc[i] += er[j].w * bf2f(x[j].u[i]);
    }
    for (; e < e1; ++e) {
        EdgeRec ea = ep[e];
        U8 xa;
        xa.v = *(const int4*)&txb[(size_t)ea.s * RS + SRC + fo];
#pragma unroll
        for (int i = 0; i < 8; ++i) acc[i] += ea.w * bf2f(xa.u[i]);
    }
    U8 o;
    if (PASS == 1) {
#pragma unroll
        for (int i = 0; i < 8; ++i) o.u[i] = f2bf(acc[i]);
        *(int4*)&txb[(size_t)node * RS + F + fo] = o.v;
    } else {
        U8 x0;
        x0.v = *(const int4*)&txb[(size_t)node * RS + fo];
#pragma unroll
        for (int i = 0; i < 8; ++i) o.u[i] = f2bf(2.f * acc[i] - bf2f(x0.u[i]));
        *(int4*)&txb[(size_t)node * RS + 2 * F + fo] = o.v;
    }
}

// W [K x Nout] f32 -> Wt [Nout x K] bf16
__global__ void convw_kernel(const float* __restrict__ W, ushort_t* __restrict__ Wt, int K, int Nout) {
    int id = blockIdx.x * blockDim.x + threadIdx.x;
    if (id >= K * Nout) return;
    int n = id / K, k = id % K;
    Wt[id] = f2bf(W[(size_t)k * Nout + n]);
}

// ---------------- bf16 MFMA GEMM: out = relu(A @ B + bias) ----------------
// 128x128 tile, BK=32, double-buffered, T4 counted-vmcnt pipeline:
//   iter k: stage(buf^1) ; s_waitcnt vmcnt(4) [older buf's loads done, prefetch stays
//   in flight] ; s_barrier ; ds_read+MFMA(buf) ; bare s_barrier ; swap.
// XOR-swizzled 16B slots via pre-swizzled global source; chunked XCD swizzle.
template <bool BF16OUT, int NY>
__global__ __launch_bounds__(256, 3) void gemm_kernel(const ushort_t* __restrict__ A,
                                                      const ushort_t* __restrict__ Bt,
                                                      const float* __restrict__ bias,
                                                      void* __restrict__ outp,
                                                      int M, int K, int Nout, int ostride,
                                                      int nwg) {
    __shared__ ushort_t As[2][128 * 32];
    __shared__ ushort_t Bs[2][128 * 32];
    int tid = threadIdx.x;
    int orig = blockIdx.x;
    int q = nwg >> 3, r = nwg & 7;
    int xcd = orig & 7, m8 = orig >> 3;
    int t = (xcd < r ? xcd * (q + 1) : r * (q + 1) + (xcd - r) * q) + m8;
    int brow = (t / NY) * 128;
    int bcol = (t % NY) * 128;

    int lane = tid & 63, w = tid >> 6;
    int wr = w >> 1, wc = w & 1;
    int g = lane >> 4, lr = lane & 15;
    f32x4 acc[4][4] = {};

    int srow[2], scol[2];
#pragma unroll
    for (int p = 0; p < 2; ++p) {
        int row = (p * 4 + w) * 16 + (lane >> 2);
        srow[p] = row;
        scol[p] = ((lane & 3) ^ ((row >> 1) & 3)) * 8;
    }

    size_t abase[2], bbase[2];
#pragma unroll
    for (int p = 0; p < 2; ++p) {
        int ar = brow + srow[p]; ar = ar < M ? ar : M - 1;
        abase[p] = (size_t)ar * K + scol[p];
        bbase[p] = (size_t)(bcol + srow[p]) * K + scol[p];
    }

    auto stage = [&](int buf, int kt) {
#pragma unroll
        for (int p = 0; p < 2; ++p) {
            gload16(&A[abase[p] + kt], &As[buf][(p * 4 + w) * 512]);
            gload16(&Bt[bbase[p] + kt], &Bs[buf][(p * 4 + w) * 512]);
        }
    };

    int aoff[4], boff4[4];
#pragma unroll
    for (int m = 0; m < 4; ++m) {
        int row = wr * 64 + m * 16 + lr;
        aoff[m] = row * 32 + ((g ^ ((row >> 1) & 3)) * 8);
    }
#pragma unroll
    for (int n = 0; n < 4; ++n) {
        int row = wc * 64 + n * 16 + lr;
        boff4[n] = row * 32 + ((g ^ ((row >> 1) & 3)) * 8);
    }

    stage(0, 0);  // 4 loads -> buf0
    int cur = 0;
    for (int kt = 0; kt < K; kt += 32) {
        if (kt + 32 < K) {
            stage(cur ^ 1, kt + 32);  // 4 more loads in flight -> buf^1
            asm volatile("s_waitcnt vmcnt(4)" ::: "memory");  // cur's 4 landed; prefetch flies
        } else {
            asm volatile("s_waitcnt vmcnt(0)" ::: "memory");  // last tile: drain all
        }
        __builtin_amdgcn_s_barrier();  // all waves' cur-buf loads landed
        bf16x8 a[4], b[4];
#pragma unroll
        for (int m = 0; m < 4; ++m) a[m] = *(const bf16x8*)&As[cur][aoff[m]];
#pragma unroll
        for (int n = 0; n < 4; ++n) b[n] = *(const bf16x8*)&Bs[cur][boff4[n]];
#pragma unroll
        for (int m = 0; m < 4; ++m)
#pragma unroll
            for (int n = 0; n < 4; ++n)
                acc[m][n] = __builtin_amdgcn_mfma_f32_16x16x32_bf16(a[m], b[n], acc[m][n], 0, 0, 0);
        __builtin_amdgcn_s_barrier();  // everyone done reading cur -> next iter may stage it
        cur ^= 1;
    }

#pragma unroll
    for (int m = 0; m < 4; ++m) {
        int grow_base = brow + wr * 64 + m * 16 + g * 4;
#pragma unroll
        for (int n = 0; n < 4; ++n) {
            int gcol = bcol + wc * 64 + n * 16 + lr;
            float bv = bias[gcol];
#pragma unroll
            for (int r2 = 0; r2 < 4; ++r2) {
                int grow = grow_base + r2;
                if (grow < M) {
                    float v2 = acc[m][n][r2] + bv;
                    v2 = v2 > 0.f ? v2 : 0.f;
                    if (BF16OUT)
                        ((ushort_t*)outp)[(size_t)grow * ostride + gcol] = f2bf(v2);
                    else
                        ((float*)outp)[(size_t)grow * ostride + gcol] = v2;
                }
            }
        }
    }
}

extern "C" void kernel_launch(void* const* d_in, const int* in_sizes, int n_in,
                              void* d_out, int out_size, void* d_ws, size_t ws_size,
                              hipStream_t stream) {
    const float* v  = (const float*)d_in[0];
    const int*   ei = (const int*)d_in[1];
    const float* W1 = (const float*)d_in[2];
    const float* b1 = (const float*)d_in[3];
    const float* W2 = (const float*)d_in[4];
    const float* b2 = (const float*)d_in[5];
    const float* W3 = (const float*)d_in[6];
    const float* b3 = (const float*)d_in[7];

    const int N = in_sizes[0] / 32;
    const int E = in_sizes[1] / 2;
    const int* src = ei;
    const int* dst = ei + E;

    char* ws = (char*)d_ws;
    size_t off = 0;
    auto alloc = [&](size_t bytes) {
        off = (off + 255) & ~(size_t)255;
        char* p = ws + off;
        off += bytes;
        return p;
    };
    EdgeRec*  ep      = (EdgeRec*)alloc((size_t)E * 8);
    int*      row_ptr = (int*)alloc((size_t)(N + 1) * 4);
    int*      wofs    = (int*)alloc((size_t)N * 4);
    int*      cnt_src = (int*)alloc((size_t)N * 4);
    int*      cnt_dst = (int*)alloc((size_t)N * 4);
    float*    dinv    = (float*)alloc((size_t)N * 4);
    int*      bsum    = (int*)alloc((size_t)256 * 4);
    int*      boff    = (int*)alloc((size_t)256 * 4);
    ushort_t* Wt      = (ushort_t*)alloc((size_t)512 * 768 * 2);
    ushort_t* txb3    = (ushort_t*)alloc((size_t)N * 768 * 2);  // [N x 768] bf16, 76.8MB
    ushort_t* txb1    = txb3;               // [N x 96] aliases txb3 (dead before gemm2)
    ushort_t* txb2    = (ushort_t*)d_out;   // [N x 384] in d_out; dead before gemm3 writes
    float*    outF    = (float*)d_out;

    const int nb = (N + 255) / 256;

    // ---- graph build ----
    hipMemsetAsync(cnt_src, 0, (size_t)N * 4, stream);
    hipMemsetAsync(cnt_dst, 0, (size_t)N * 4, stream);
    count_kernel<<<(E + 255) / 256, 256, 0, stream>>>(src, dst, cnt_src, cnt_dst, E, N);
    dinv_kernel<<<(N + 255) / 256, 256, 0, stream>>>(cnt_src, dinv, N);
    blocksum_kernel<<<nb, 256, 0, stream>>>(cnt_dst, bsum, N);
    scanblock_kernel<<<1, 256, 0, stream>>>(bsum, boff, nb);
    scatter_scan_kernel<<<nb, 256, 0, stream>>>(cnt_dst, boff, row_ptr, wofs, N);
    fill_kernel<<<(E + 255) / 256, 256, 0, stream>>>(src, dst, dinv, wofs, ep, E, N);

    const int mt = (N + 127) / 128;  // 391 row panels

    // ---- layer 1: 32 -> 128 ----
    convin_kernel<<<(N * 4 + 255) / 256, 256, 0, stream>>>(v, txb1, N);
    prop_kernel<32, 1><<<(N + 63) / 64, 256, 0, stream>>>(txb1, row_ptr, ep, N);
    prop_kernel<32, 2><<<(N + 63) / 64, 256, 0, stream>>>(txb1, row_ptr, ep, N);
    convw_kernel<<<(96 * 128 + 255) / 256, 256, 0, stream>>>(W1, Wt, 96, 128);
    gemm_kernel<true, 1><<<mt * 1, 256, 0, stream>>>(txb1, Wt, b1, txb2, N, 96, 128, 384, mt * 1);

    // ---- layer 2: 128 -> 256 ----
    prop_kernel<128, 1><<<(N + 15) / 16, 256, 0, stream>>>(txb2, row_ptr, ep, N);
    prop_kernel<128, 2><<<(N + 15) / 16, 256, 0, stream>>>(txb2, row_ptr, ep, N);
    convw_kernel<<<(384 * 256 + 255) / 256, 256, 0, stream>>>(W2, Wt, 384, 256);
    gemm_kernel<true, 2><<<mt * 2, 256, 0, stream>>>(txb2, Wt, b2, txb3, N, 384, 256, 768, mt * 2);

    // ---- layer 3: 256 -> 512 ----
    prop_kernel<256, 1><<<(N + 7) / 8, 256, 0, stream>>>(txb3, row_ptr, ep, N);
    prop_kernel<256, 2><<<(N + 7) / 8, 256, 0, stream>>>(txb3, row_ptr, ep, N);
    convw_kernel<<<(768 * 512 + 255) / 256, 256, 0, stream>>>(W3, Wt, 768, 512);
    gemm_kernel<false, 4><<<mt * 4, 256, 0, stream>>>(txb3, Wt, b3, outF, N, 768, 512, 512, mt * 4);
}

// Round 8
// 443.289 us; speedup vs baseline: 2.9738x; 1.0232x over previous
//
#include <hip/hip_runtime.h>
#include <hip/hip_bf16.h>

// SpectralMoleculeEncoder: 3-layer ChebConv (K=3), N=50000, E=800000, 32->128->256->512.
// R8: (a) prop masked-batch pipeline: uniform batches of 4 edges (invalid lanes w=0),
// next batch's EdgeRecs prefetched during current batch's gather latency, no serial tail;
// (b) weight folding out = x(W0-W2) + (Px)W1 + (PPx)(2W2): prop2 writes just P(slice1),
// fold done in f32 inside convw; (c) gemm __launch_bounds__(256,4) for 4 blocks/CU.

typedef __bf16 bf16x8 __attribute__((ext_vector_type(8)));
typedef float f32x4 __attribute__((ext_vector_type(4)));
typedef unsigned short ushort_t;

struct EdgeRec { int s; float w; };

__device__ inline float bf2f(ushort_t u) { return __builtin_bit_cast(float, (unsigned)u << 16); }
__device__ inline ushort_t f2bf(float f) { return __builtin_bit_cast(ushort_t, (__bf16)f); }

union U8 { int4 v; ushort_t u[8]; };

__device__ inline void gload16(const ushort_t* g, ushort_t* l) {
    __builtin_amdgcn_global_load_lds(
        (const __attribute__((address_space(1))) unsigned int*)g,
        (__attribute__((address_space(3))) unsigned int*)l, 16, 0, 0);
}

// ---------------- graph build ----------------
__global__ void count_kernel(const int* __restrict__ src, const int* __restrict__ dst,
                             int* __restrict__ cnt_src, int* __restrict__ cnt_dst, int E, int N) {
    int e = blockIdx.x * blockDim.x + threadIdx.x;
    if (e >= E) return;
    int s = src[e], d = dst[e];
    if ((unsigned)s < (unsigned)N) atomicAdd(&cnt_src[s], 1);
    if ((unsigned)d < (unsigned)N) atomicAdd(&cnt_dst[d], 1);
}

__global__ void dinv_kernel(const int* __restrict__ cnt_src, float* __restrict__ dinv, int N) {
    int i = blockIdx.x * blockDim.x + threadIdx.x;
    if (i >= N) return;
    int c = cnt_src[i];
    dinv[i] = (c > 0) ? rsqrtf((float)c) : 0.0f;
}

// ---- hierarchical exclusive scan of cnt[N] -> row_ptr[N+1], wofs[N] ----
__global__ void blocksum_kernel(const int* __restrict__ cnt, int* __restrict__ bsum, int N) {
    int i = blockIdx.x * 256 + threadIdx.x;
    int v = (i < N) ? cnt[i] : 0;
#pragma unroll
    for (int off = 32; off >= 1; off >>= 1) v += __shfl_xor(v, off);
    __shared__ int ws[4];
    if ((threadIdx.x & 63) == 0) ws[threadIdx.x >> 6] = v;
    __syncthreads();
    if (threadIdx.x == 0) bsum[blockIdx.x] = ws[0] + ws[1] + ws[2] + ws[3];
}

__global__ void scanblock_kernel(const int* __restrict__ bsum, int* __restrict__ boff, int nb) {
    __shared__ int s[256];
    int t = threadIdx.x;
    int v = (t < nb) ? bsum[t] : 0;
    s[t] = v;
    __syncthreads();
#pragma unroll
    for (int off = 1; off < 256; off <<= 1) {
        int u = (t >= off) ? s[t - off] : 0;
        __syncthreads();
        s[t] += u;
        __syncthreads();
    }
    if (t < nb) boff[t] = s[t] - v;  // exclusive
}

__global__ void scatter_scan_kernel(const int* __restrict__ cnt, const int* __restrict__ boff,
                                    int* __restrict__ row_ptr, int* __restrict__ wofs, int N) {
    __shared__ int s[256];
    int t = threadIdx.x;
    int i = blockIdx.x * 256 + t;
    int v = (i < N) ? cnt[i] : 0;
    s[t] = v;
    __syncthreads();
#pragma unroll
    for (int off = 1; off < 256; off <<= 1) {
        int u = (t >= off) ? s[t - off] : 0;
        __syncthreads();
        s[t] += u;
        __syncthreads();
    }
    int run = boff[blockIdx.x] + s[t] - v;
    if (i < N) { row_ptr[i] = run; wofs[i] = run; }
    else if (i == N) row_ptr[N] = run;
}

__global__ void fill_kernel(const int* __restrict__ src, const int* __restrict__ dst,
                            const float* __restrict__ dinv, int* __restrict__ wofs,
                            EdgeRec* __restrict__ ep, int E, int N) {
    int e = blockIdx.x * blockDim.x + threadIdx.x;
    if (e >= E) return;
    int s = src[e], d = dst[e];
    if ((unsigned)s >= (unsigned)N || (unsigned)d >= (unsigned)N) return;
    int pos = atomicAdd(&wofs[d], 1);
    EdgeRec er; er.s = s; er.w = -dinv[s] * dinv[d];
    ep[pos] = er;
}

// v [N,32] f32 -> txb1 slice0 bf16 (row stride 96)
__global__ void convin_kernel(const float* __restrict__ v, ushort_t* __restrict__ txb, int N) {
    int id = blockIdx.x * blockDim.x + threadIdx.x;
    if (id >= N * 4) return;
    int node = id >> 2, c = (id & 3) << 3;
    const float* p = &v[(size_t)node * 32 + c];
    U8 o;
#pragma unroll
    for (int i = 0; i < 8; ++i) o.u[i] = f2bf(p[i]);
    *(int4*)&txb[(size_t)node * 96 + c] = o.v;
}

// ---------------- propagation (CSR gather, bf16, 16B/lane) ----------------
// PASS 1: slice1 = P slice0 ; PASS 2: slice2 = P slice1  (weights folded: 2W2 in Wt)
// Masked uniform batches of U=4 edges; next batch's EdgeRecs prefetched during
// current batch's gathers; no serial tail (invalid lanes: clamped idx, w=0).
template <int F, int PASS>
__global__ __launch_bounds__(256) void prop_kernel(ushort_t* __restrict__ txb,
                                                   const int* __restrict__ row_ptr,
                                                   const EdgeRec* __restrict__ ep, int N) {
    constexpr int U = 4;
    constexpr int T = F / 8;        // lanes per node
    constexpr int NPB = 256 / T;    // nodes per block
    constexpr int RS = 3 * F;       // txb row stride
    constexpr int SRC = (PASS == 1) ? 0 : F;
    int tf = threadIdx.x % T;
    int node = blockIdx.x * NPB + threadIdx.x / T;
    if (node >= N) return;
    int e0 = row_ptr[node], e1 = row_ptr[node + 1];
    int fo = tf * 8;
    float acc[8] = {};
    int deg = e1 - e0;
    if (deg > 0) {
        int nbatch = (deg + U - 1) / U;
        EdgeRec cur[U], nxt[U];
#pragma unroll
        for (int j = 0; j < U; ++j) {
            int ei = e0 + j;
            EdgeRec rr = ep[ei < e1 ? ei : e1 - 1];
            if (ei >= e1) rr.w = 0.f;
            cur[j] = rr;
        }
        for (int b = 0; b < nbatch; ++b) {
            U8 x[U];
#pragma unroll
            for (int j = 0; j < U; ++j)
                x[j].v = *(const int4*)&txb[(size_t)cur[j].s * RS + SRC + fo];
            if (b + 1 < nbatch) {
                int nbase = e0 + (b + 1) * U;
#pragma unroll
                for (int j = 0; j < U; ++j) {
                    int ei = nbase + j;
                    EdgeRec rr = ep[ei < e1 ? ei : e1 - 1];
                    if (ei >= e1) rr.w = 0.f;
                    nxt[j] = rr;
                }
            }
#pragma unroll
            for (int j = 0; j < U; ++j)
#pragma unroll
                for (int i = 0; i < 8; ++i) acc[i] += cur[j].w * bf2f(x[j].u[i]);
#pragma unroll
            for (int j = 0; j < U; ++j) cur[j] = nxt[j];
        }
    }
    U8 o;
#pragma unroll
    for (int i = 0; i < 8; ++i) o.u[i] = f2bf(acc[i]);
    *(int4*)&txb[(size_t)node * RS + (PASS == 1 ? F : 2 * F) + fo] = o.v;
}

// Folded weights: W [3F x Nout] f32 -> Wt [Nout x 3F] bf16 with
// rows [0,F): W0-W2 ; [F,2F): W1 ; [2F,3F): 2*W2   (fold exact in f32)
__global__ void convw_kernel(const float* __restrict__ W, ushort_t* __restrict__ Wt,
                             int F, int Nout) {
    int K = 3 * F;
    int id = blockIdx.x * blockDim.x + threadIdx.x;
    if (id >= K * Nout) return;
    int n = id / K, k = id % K;
    float val;
    if (k < F)            val = W[(size_t)k * Nout + n] - W[(size_t)(2 * F + k) * Nout + n];
    else if (k < 2 * F)   val = W[(size_t)k * Nout + n];
    else                  val = 2.0f * W[(size_t)k * Nout + n];
    Wt[id] = f2bf(val);
}

// ---------------- bf16 MFMA GEMM: out = relu(A @ B + bias) ----------------
// 128x128 tile, BK=32, double-buffered, counted-vmcnt pipeline (vmcnt(4) keeps next
// tile's 4 gload_lds in flight across the barrier). XOR-swizzled 16B slots via
// pre-swizzled global source; chunked bijective XCD swizzle; 4 blocks/CU target.
template <bool BF16OUT, int NY>
__global__ __launch_bounds__(256, 4) void gemm_kernel(const ushort_t* __restrict__ A,
                                                      const ushort_t* __restrict__ Bt,
                                                      const float* __restrict__ bias,
                                                      void* __restrict__ outp,
                                                      int M, int K, int Nout, int ostride,
                                                      int nwg) {
    __shared__ ushort_t As[2][128 * 32];
    __shared__ ushort_t Bs[2][128 * 32];
    int tid = threadIdx.x;
    int orig = blockIdx.x;
    int q = nwg >> 3, r = nwg & 7;
    int xcd = orig & 7, m8 = orig >> 3;
    int t = (xcd < r ? xcd * (q + 1) : r * (q + 1) + (xcd - r) * q) + m8;
    int brow = (t / NY) * 128;
    int bcol = (t % NY) * 128;

    int lane = tid & 63, w = tid >> 6;
    int wr = w >> 1, wc = w & 1;
    int g = lane >> 4, lr = lane & 15;
    f32x4 acc[4][4] = {};

    int srow[2], scol[2];
#pragma unroll
    for (int p = 0; p < 2; ++p) {
        int row = (p * 4 + w) * 16 + (lane >> 2);
        srow[p] = row;
        scol[p] = ((lane & 3) ^ ((row >> 1) & 3)) * 8;
    }

    size_t abase[2], bbase[2];
#pragma unroll
    for (int p = 0; p < 2; ++p) {
        int ar = brow + srow[p]; ar = ar < M ? ar : M - 1;
        abase[p] = (size_t)ar * K + scol[p];
        bbase[p] = (size_t)(bcol + srow[p]) * K + scol[p];
    }

    auto stage = [&](int buf, int kt) {
#pragma unroll
        for (int p = 0; p < 2; ++p) {
            gload16(&A[abase[p] + kt], &As[buf][(p * 4 + w) * 512]);
            gload16(&Bt[bbase[p] + kt], &Bs[buf][(p * 4 + w) * 512]);
        }
    };

    int aoff[4], boff4[4];
#pragma unroll
    for (int m = 0; m < 4; ++m) {
        int row = wr * 64 + m * 16 + lr;
        aoff[m] = row * 32 + ((g ^ ((row >> 1) & 3)) * 8);
    }
#pragma unroll
    for (int n = 0; n < 4; ++n) {
        int row = wc * 64 + n * 16 + lr;
        boff4[n] = row * 32 + ((g ^ ((row >> 1) & 3)) * 8);
    }

    stage(0, 0);  // 4 loads -> buf0
    int cur = 0;
    for (int kt = 0; kt < K; kt += 32) {
        if (kt + 32 < K) {
            stage(cur ^ 1, kt + 32);  // 4 more loads in flight -> buf^1
            asm volatile("s_waitcnt vmcnt(4)" ::: "memory");  // cur's 4 landed; prefetch flies
        } else {
            asm volatile("s_waitcnt vmcnt(0)" ::: "memory");  // last tile: drain all
        }
        __builtin_amdgcn_s_barrier();  // all waves' cur-buf loads landed
        bf16x8 a[4], b[4];
#pragma unroll
        for (int m = 0; m < 4; ++m) a[m] = *(const bf16x8*)&As[cur][aoff[m]];
#pragma unroll
        for (int n = 0; n < 4; ++n) b[n] = *(const bf16x8*)&Bs[cur][boff4[n]];
#pragma unroll
        for (int m = 0; m < 4; ++m)
#pragma unroll
            for (int n = 0; n < 4; ++n)
                acc[m][n] = __builtin_amdgcn_mfma_f32_16x16x32_bf16(a[m], b[n], acc[m][n], 0, 0, 0);
        __builtin_amdgcn_s_barrier();  // everyone done reading cur -> next iter may stage it
        cur ^= 1;
    }

#pragma unroll
    for (int m = 0; m < 4; ++m) {
        int grow_base = brow + wr * 64 + m * 16 + g * 4;
#pragma unroll
        for (int n = 0; n < 4; ++n) {
            int gcol = bcol + wc * 64 + n * 16 + lr;
            float bv = bias[gcol];
#pragma unroll
            for (int r2 = 0; r2 < 4; ++r2) {
                int grow = grow_base + r2;
                if (grow < M) {
                    float v2 = acc[m][n][r2] + bv;
                    v2 = v2 > 0.f ? v2 : 0.f;
                    if (BF16OUT)
                        ((ushort_t*)outp)[(size_t)grow * ostride + gcol] = f2bf(v2);
                    else
                        ((float*)outp)[(size_t)grow * ostride + gcol] = v2;
                }
            }
        }
    }
}

extern "C" void kernel_launch(void* const* d_in, const int* in_sizes, int n_in,
                              void* d_out, int out_size, void* d_ws, size_t ws_size,
                              hipStream_t stream) {
    const float* v  = (const float*)d_in[0];
    const int*   ei = (const int*)d_in[1];
    const float* W1 = (const float*)d_in[2];
    const float* b1 = (const float*)d_in[3];
    const float* W2 = (const float*)d_in[4];
    const float* b2 = (const float*)d_in[5];
    const float* W3 = (const float*)d_in[6];
    const float* b3 = (const float*)d_in[7];

    const int N = in_sizes[0] / 32;
    const int E = in_sizes[1] / 2;
    const int* src = ei;
    const int* dst = ei + E;

    char* ws = (char*)d_ws;
    size_t off = 0;
    auto alloc = [&](size_t bytes) {
        off = (off + 255) & ~(size_t)255;
        char* p = ws + off;
        off += bytes;
        return p;
    };
    EdgeRec*  ep      = (EdgeRec*)alloc((size_t)E * 8);
    int*      row_ptr = (int*)alloc((size_t)(N + 1) * 4);
    int*      wofs    = (int*)alloc((size_t)N * 4);
    int*      cnt_src = (int*)alloc((size_t)N * 4);
    int*      cnt_dst = (int*)alloc((size_t)N * 4);
    float*    dinv    = (float*)alloc((size_t)N * 4);
    int*      bsum    = (int*)alloc((size_t)256 * 4);
    int*      boff    = (int*)alloc((size_t)256 * 4);
    ushort_t* Wt      = (ushort_t*)alloc((size_t)512 * 768 * 2);
    ushort_t* txb3    = (ushort_t*)alloc((size_t)N * 768 * 2);  // [N x 768] bf16, 76.8MB
    ushort_t* txb1    = txb3;               // [N x 96] aliases txb3 (dead before gemm2)
    ushort_t* txb2    = (ushort_t*)d_out;   // [N x 384] in d_out; dead before gemm3 writes
    float*    outF    = (float*)d_out;

    const int nb = (N + 255) / 256;

    // ---- graph build ----
    hipMemsetAsync(cnt_src, 0, (size_t)N * 4, stream);
    hipMemsetAsync(cnt_dst, 0, (size_t)N * 4, stream);
    count_kernel<<<(E + 255) / 256, 256, 0, stream>>>(src, dst, cnt_src, cnt_dst, E, N);
    dinv_kernel<<<(N + 255) / 256, 256, 0, stream>>>(cnt_src, dinv, N);
    blocksum_kernel<<<nb, 256, 0, stream>>>(cnt_dst, bsum, N);
    scanblock_kernel<<<1, 256, 0, stream>>>(bsum, boff, nb);
    scatter_scan_kernel<<<nb, 256, 0, stream>>>(cnt_dst, boff, row_ptr, wofs, N);
    fill_kernel<<<(E + 255) / 256, 256, 0, stream>>>(src, dst, dinv, wofs, ep, E, N);

    const int mt = (N + 127) / 128;  // 391 row panels

    // ---- layer 1: 32 -> 128 ----
    convin_kernel<<<(N * 4 + 255) / 256, 256, 0, stream>>>(v, txb1, N);
    prop_kernel<32, 1><<<(N + 63) / 64, 256, 0, stream>>>(txb1, row_ptr, ep, N);
    prop_kernel<32, 2><<<(N + 63) / 64, 256, 0, stream>>>(txb1, row_ptr, ep, N);
    convw_kernel<<<(96 * 128 + 255) / 256, 256, 0, stream>>>(W1, Wt, 32, 128);
    gemm_kernel<true, 1><<<mt * 1, 256, 0, stream>>>(txb1, Wt, b1, txb2, N, 96, 128, 384, mt * 1);

    // ---- layer 2: 128 -> 256 ----
    prop_kernel<128, 1><<<(N + 15) / 16, 256, 0, stream>>>(txb2, row_ptr, ep, N);
    prop_kernel<128, 2><<<(N + 15) / 16, 256, 0, stream>>>(txb2, row_ptr, ep, N);
    convw_kernel<<<(384 * 256 + 255) / 256, 256, 0, stream>>>(W2, Wt, 128, 256);
    gemm_kernel<true, 2><<<mt * 2, 256, 0, stream>>>(txb2, Wt, b2, txb3, N, 384, 256, 768, mt * 2);

    // ---- layer 3: 256 -> 512 ----
    prop_kernel<256, 1><<<(N + 7) / 8, 256, 0, stream>>>(txb3, row_ptr, ep, N);
    prop_kernel<256, 2><<<(N + 7) / 8, 256, 0, stream>>>(txb3, row_ptr, ep, N);
    convw_kernel<<<(768 * 512 + 255) / 256, 256, 0, stream>>>(W3, Wt, 256, 512);
    gemm_kernel<false, 4><<<mt * 4, 256, 0, stream>>>(txb3, Wt, b3, outF, N, 768, 512, 512, mt * 4);
}